// Round 10
// baseline (405.095 us; speedup 1.0000x reference)
//
#include <hip/hip_runtime.h>
#include <hip/hip_bf16.h>

// Shapes (fixed by the reference)
#define B_  16
#define S_  512
#define D_  256
#define H_  8
#define L_  4
#define K_  16
#define N_  (B_ * S_)     // 8192
#define E_  65536
#define NE_ 32768
#define DFF_ 512
#define HD_ 32

typedef __attribute__((ext_vector_type(8))) __bf16 bf16x8;
typedef __attribute__((ext_vector_type(4))) __bf16 bf16x4;
typedef __attribute__((ext_vector_type(4))) float f32x4;

// async global->LDS, 16B per lane. LDS dest must be lane-contiguous (base+lane*16).
__device__ __forceinline__ void gl2lds16(const void* g, void* l) {
    __builtin_amdgcn_global_load_lds(
        (const __attribute__((address_space(1))) unsigned int*)g,
        (__attribute__((address_space(3))) unsigned int*)l, 16, 0, 0);
}

#define QSCALE 0.17677669529663688f   // 1/sqrt(32), folded into wq/bq

// ---------------------------------------------------------------------------
// Combined fp32 -> bf16 conversion for weights (1 launch) + cnt zeroing.
// ipw/ow/fw1/fw2 are stored MFMA-FRAGMENT-SWIZZLED: fragment (rg, kc) holds,
// at lane l, elements W[rg*16 + (l&15)][kc*32 + (l>>4)*8 .. +8], flat address
// layer_base + (rg*KC + kc)*512 + l*8. A wave's fragment load is then one
// contiguous 1 KB read (perfect coalescing, no LDS staging needed).
// ---------------------------------------------------------------------------
__global__ __launch_bounds__(256) void convert_all(
    const float* __restrict__ ipw, __bf16* __restrict__ ipwf_bf,
    const float* __restrict__ ow,  __bf16* __restrict__ ow_bf,
    const float* __restrict__ fw1, __bf16* __restrict__ fw1_bf,
    const float* __restrict__ fw2, __bf16* __restrict__ fw2_bf,
    const float* __restrict__ mw1, const float* __restrict__ mw2,
    __bf16* __restrict__ wcat_bf,
    const float* __restrict__ ptw, const float* __restrict__ pew,
    __bf16* __restrict__ wp_bf,
    const float* __restrict__ ipb, float* __restrict__ ipb_s,
    int* __restrict__ cnt)
{
    int blk = blockIdx.x;
    if (blk < 768) {
        // in_proj_w with q-row scaling -> frag-swizzled (K chunks = 8)
        size_t i = ((size_t)blk * 256 + threadIdx.x) * 4;
        int row = (int)((i >> 8) % 768);
        int layer = (int)(i / 196608);
        int col = (int)(i & 255);
        float sc = (row < 256) ? QSCALE : 1.0f;
        float4 v = *(const float4*)(ipw + i);
        bf16x4 o = {(__bf16)(v.x * sc), (__bf16)(v.y * sc),
                    (__bf16)(v.z * sc), (__bf16)(v.w * sc)};
        size_t dsti = (size_t)layer * 196608
                    + (size_t)(((((row >> 4) * 8) + (col >> 5)) << 9)
                               + ((col & 31) >> 3) * 128 + (row & 15) * 8 + (col & 7));
        *(bf16x4*)(ipwf_bf + dsti) = o;
    } else if (blk < 2048) {
        // ow / fw1 / fw2 -> fragment-swizzled bf16
        const float* src; __bf16* dst; int base;
        if      (blk < 1024)  { src = ow;   dst = ow_bf;   base = blk - 768; }
        else if (blk < 1536)  { src = fw1;  dst = fw1_bf;  base = blk - 1024; }
        else                  { src = fw2;  dst = fw2_bf;  base = blk - 1536; }
        size_t i = ((size_t)base * 256 + threadIdx.x) * 4;
        float4 v = *(const float4*)(src + i);
        int layer, row, col, kchunks; size_t lstride;
        if (blk < 1024) {            // ow: 4 x [256 x 256]
            layer = (int)(i >> 16); int idx = (int)(i & 65535);
            row = idx >> 8; col = idx & 255; kchunks = 8; lstride = 65536;
        } else if (blk < 1536) {     // fw1: 4 x [512 x 256]
            layer = (int)(i >> 17); int idx = (int)(i & 131071);
            row = idx >> 8; col = idx & 255; kchunks = 8; lstride = 131072;
        } else {                     // fw2: 4 x [256 x 512]
            layer = (int)(i >> 17); int idx = (int)(i & 131071);
            row = idx >> 9; col = idx & 511; kchunks = 16; lstride = 131072;
        }
        size_t dsti = (size_t)layer * lstride
                    + (size_t)((((row >> 4) * kchunks + (col >> 5)) << 9)
                               + ((col & 31) >> 3) * 128 + (row & 15) * 8 + (col & 7));
        bf16x4 o = {(__bf16)v.x, (__bf16)v.y, (__bf16)v.z, (__bf16)v.w};
        *(bf16x4*)(dst + dsti) = o;
    } else if (blk < 2176) {
        int isw2 = blk >= 2112;
        int base = blk - (isw2 ? 2112 : 2048);
        const float* src = isw2 ? mw2 : mw1;
        size_t i = ((size_t)base * 256 + threadIdx.x) * 4;   // elem in [256x256]
        int row = i >> 8, col = i & 255;
        float4 v = *(const float4*)(src + i);
        bf16x4 o = {(__bf16)v.x, (__bf16)v.y, (__bf16)v.z, (__bf16)v.w};
        *(bf16x4*)(wcat_bf + (size_t)row * 512 + (isw2 ? 256 : 0) + col) = o;
    } else if (blk < 2184) {
        int base = blk - 2176;
        size_t i = ((size_t)base * 256 + threadIdx.x) * 4;
        int row = i >> 8, col = i & 255;
        float4 v = make_float4(0.f, 0.f, 0.f, 0.f);
        if (row < 16)       v = *(const float4*)(ptw + row * 256 + col);
        else if (row == 16) v = *(const float4*)(pew + col);
        bf16x4 o = {(__bf16)v.x, (__bf16)v.y, (__bf16)v.z, (__bf16)v.w};
        *(bf16x4*)(wp_bf + i) = o;
    } else if (blk < 2187) {
        // scaled in_proj bias: 4*768 = 3072 floats, 3 blocks
        int base = blk - 2184;
        size_t i = ((size_t)base * 256 + threadIdx.x) * 4;
        if (i < 3072) {
            float sc = ((i % 768) < 256) ? QSCALE : 1.0f;
            float4 v = *(const float4*)(ipb + i);
            *(float4*)(ipb_s + i) = make_float4(v.x * sc, v.y * sc, v.z * sc, v.w * sc);
        }
    } else {
        int base = blk - 2187;
        int4* p = (int4*)(cnt + ((size_t)base * 256 + threadIdx.x) * 4);
        *p = make_int4(0, 0, 0, 0);
    }
}

// ---------------------------------------------------------------------------
// CSR build over destination nodes: histogram -> scan -> bucket fill.
// ---------------------------------------------------------------------------
__global__ __launch_bounds__(256) void hist_kernel(
    const int* __restrict__ inc, int* __restrict__ cnt)
{
    int e = blockIdx.x * 256 + threadIdx.x;
    atomicAdd(&cnt[inc[e]], 1);
}

__global__ __launch_bounds__(256) void scan_kernel(
    const int* __restrict__ cnt, int* __restrict__ row_ptr, int* __restrict__ ofs)
{
    __shared__ int part[256];
    int t = threadIdx.x;
    int base = t * 32, sum = 0;
    int local[32];
    #pragma unroll
    for (int j = 0; j < 32; ++j) { local[j] = cnt[base + j]; sum += local[j]; }
    part[t] = sum;
    __syncthreads();
    #pragma unroll
    for (int off = 1; off < 256; off <<= 1) {
        int other = (t >= off) ? part[t - off] : 0;
        __syncthreads();
        part[t] += other;
        __syncthreads();
    }
    int run = part[t] - sum;   // exclusive prefix
    for (int j = 0; j < 32; ++j) {
        row_ptr[base + j] = run;
        ofs[base + j] = run;
        run += local[j];
    }
    if (t == 255) row_ptr[8192] = run;
}

__global__ __launch_bounds__(256) void fill_kernel(
    const int* __restrict__ inc, int* __restrict__ ofs, int* __restrict__ elist)
{
    int e = blockIdx.x * 256 + threadIdx.x;
    int pos = atomicAdd(&ofs[inc[e]], 1);
    elist[pos] = e;
}

// ---------------------------------------------------------------------------
// CSR gather: G_bf[n][0:256] = sum node[inc1[e]], G_bf[n][256:512] = sum
// edge[e]. One wave per node, fp32 accumulate, 2-edge unroll for MLP.
// ---------------------------------------------------------------------------
__global__ __launch_bounds__(256) void csr_gather(
    const float* __restrict__ node, const float* __restrict__ edge,
    const int* __restrict__ inc, const int* __restrict__ row_ptr,
    const int* __restrict__ elist, __bf16* __restrict__ G)
{
    int n = blockIdx.x * 4 + (threadIdx.x >> 6);
    int lane = threadIdx.x & 63;
    int s = row_ptr[n], epos = row_ptr[n + 1];
    float4 an = {0.f, 0.f, 0.f, 0.f}, ae = {0.f, 0.f, 0.f, 0.f};
    int i = s;
    for (; i + 2 <= epos; i += 2) {
        int e0 = elist[i], e1 = elist[i + 1];
        int s0 = inc[E_ + e0], s1 = inc[E_ + e1];
        float4 nv0 = *(const float4*)(node + (size_t)s0 * 256 + lane * 4);
        float4 ev0 = *(const float4*)(edge + (size_t)e0 * 256 + lane * 4);
        float4 nv1 = *(const float4*)(node + (size_t)s1 * 256 + lane * 4);
        float4 ev1 = *(const float4*)(edge + (size_t)e1 * 256 + lane * 4);
        an.x += nv0.x + nv1.x; an.y += nv0.y + nv1.y;
        an.z += nv0.z + nv1.z; an.w += nv0.w + nv1.w;
        ae.x += ev0.x + ev1.x; ae.y += ev0.y + ev1.y;
        ae.z += ev0.z + ev1.z; ae.w += ev0.w + ev1.w;
    }
    if (i < epos) {
        int e0 = elist[i];
        int s0 = inc[E_ + e0];
        float4 nv0 = *(const float4*)(node + (size_t)s0 * 256 + lane * 4);
        float4 ev0 = *(const float4*)(edge + (size_t)e0 * 256 + lane * 4);
        an.x += nv0.x; an.y += nv0.y; an.z += nv0.z; an.w += nv0.w;
        ae.x += ev0.x; ae.y += ev0.y; ae.z += ev0.z; ae.w += ev0.w;
    }
    __bf16* g = G + (size_t)n * 512 + lane * 4;
    bf16x4 bn = {(__bf16)an.x, (__bf16)an.y, (__bf16)an.z, (__bf16)an.w};
    bf16x4 be = {(__bf16)ae.x, (__bf16)ae.y, (__bf16)ae.z, (__bf16)ae.w};
    *(bf16x4*)g = bn;
    *(bf16x4*)(g + 256) = be;
}

// ---------------------------------------------------------------------------
// QKV projection v2: 64x128 tile, A-tile staged ONCE (1 barrier), B loads
// direct from L2 in frag-swizzled order (1 KB coalesced wave reads).
// Per-layer weight L2 traffic unchanged (48 MB); barriers/block 8 -> 1.
// Accumulation ascending K=32 chunks == old staged kernel -> bit-identical.
// (R8 bug fixed: 64x256 tile = 2048 16B chunks -> rpt<8, not 4.)
// ---------------------------------------------------------------------------
__global__ __launch_bounds__(256) void qkv_frag(
    const __bf16* __restrict__ A,      // x_bf [8192 x 256]
    const __bf16* __restrict__ Wq,     // frag-swizzled in_proj [768 x 256]
    const float* __restrict__ bias,    // scaled in_proj bias [768]
    __bf16* __restrict__ C)            // qkv [8192 x 768]
{
    __shared__ __bf16 As[64 * 264];    // 33 KB A-tile (padded rows)
    int tid = threadIdx.x;
    int n0 = blockIdx.x * 128, m0 = blockIdx.y * 64;
    int w = tid >> 6, lane = tid & 63, quad = lane >> 4, r16 = lane & 15;

    // stage 64x256 A-tile (reg-staged, padded rows): 2048 chunks of 16B
    #pragma unroll
    for (int rpt = 0; rpt < 8; ++rpt) {
        int c = tid + rpt * 256;
        int row = c >> 5, cc = c & 31;
        bf16x8 v = *(const bf16x8*)(A + (size_t)(m0 + row) * 256 + cc * 8);
        *(bf16x8*)(&As[row * 264 + cc * 8]) = v;
    }
    __syncthreads();

    f32x4 acc[4][2] = {};   // [mt][nt]; wave w owns cols n0 + w*32 .. +31
    {
        const __bf16* wf = Wq + lane * 8;
        int rgbase = (n0 >> 4) + w * 2;     // fragment row-group
        #pragma unroll
        for (int kc = 0; kc < 8; ++kc) {
            bf16x8 af[4], bfr[2];
            #pragma unroll
            for (int mt = 0; mt < 4; ++mt)
                af[mt] = *(const bf16x8*)(&As[(mt * 16 + r16) * 264 + kc * 32 + quad * 8]);
            #pragma unroll
            for (int nt = 0; nt < 2; ++nt)
                bfr[nt] = *(const bf16x8*)(wf + ((((rgbase + nt) << 3) + kc) << 9));
            #pragma unroll
            for (int mt = 0; mt < 4; ++mt)
                #pragma unroll
                for (int nt = 0; nt < 2; ++nt)
                    acc[mt][nt] = __builtin_amdgcn_mfma_f32_16x16x32_bf16(
                        af[mt], bfr[nt], acc[mt][nt], 0, 0, 0);
        }
    }

    #pragma unroll
    for (int nt = 0; nt < 2; ++nt) {
        int n = n0 + w * 32 + nt * 16 + r16;
        float bv = bias[n];
        #pragma unroll
        for (int mt = 0; mt < 4; ++mt) {
            #pragma unroll
            for (int reg = 0; reg < 4; ++reg) {
                int m = m0 + mt * 16 + quad * 4 + reg;
                C[(size_t)m * 768 + n] = (__bf16)(acc[mt][nt][reg] + bv);
            }
        }
    }
}

// ---------------------------------------------------------------------------
// agreg GEMM v2 (32-row tiles, grid (2,256) = 512 blocks for 2 blocks/CU):
// x[m,n] = G_bf[m,:]·wcat[n,:] + deg(m)*msg_b[n] + node[m,n] + pos[m%512,n]
// ---------------------------------------------------------------------------
__global__ __launch_bounds__(256) void agreg_gemm(
    const __bf16* __restrict__ G, const __bf16* __restrict__ Wc,
    const int* __restrict__ row_ptr, const float* __restrict__ mb,
    const float* __restrict__ node, const float* __restrict__ pos,
    float* __restrict__ xo, __bf16* __restrict__ xo_bf)
{
    __shared__ __bf16 As0[32 * 32], As1[32 * 32];      // 2 KB each
    __shared__ __bf16 Bs0[128 * 32], Bs1[128 * 32];    // 8 KB each
    int tid = threadIdx.x;
    int m0 = blockIdx.y * 32, n0 = blockIdx.x * 128;
    int w = tid >> 6, lane = tid & 63, quad = lane >> 4, r16 = lane & 15;
    int wr = w >> 1, wc = w & 1;

    int lr = tid >> 2, lc = (tid & 3) * 8;
    const __bf16* ag  = G  + (size_t)(m0 + (tid >> 2 & 31)) * 512 + lc;
    const __bf16* bg0 = Wc + (size_t)(n0 + lr) * 512 + lc;
    const __bf16* bg1 = bg0 + (size_t)64 * 512;

    f32x4 acc[4] = {};   // [nt], wave = 16 rows x 64 cols

    for (int k0 = 0; k0 < 512; k0 += 64) {
        __syncthreads();
        if (tid < 128) {
            gl2lds16(ag + k0,      As0 + tid * 8);
            gl2lds16(ag + k0 + 32, As1 + tid * 8);
        }
        gl2lds16(bg0 + k0,       Bs0 + tid * 8);
        gl2lds16(bg1 + k0,       Bs0 + 2048 + tid * 8);
        gl2lds16(bg0 + k0 + 32,  Bs1 + tid * 8);
        gl2lds16(bg1 + k0 + 32,  Bs1 + 2048 + tid * 8);
        __syncthreads();

        #pragma unroll
        for (int kh = 0; kh < 2; ++kh) {
            const __bf16* Asr = kh ? As1 : As0;
            const __bf16* Bsr = kh ? Bs1 : Bs0;
            bf16x8 af = *(const bf16x8*)(Asr + (wr * 16 + r16) * 32 + quad * 8);
            #pragma unroll
            for (int nt = 0; nt < 4; ++nt) {
                bf16x8 bfr = *(const bf16x8*)(Bsr + (wc * 64 + nt * 16 + r16) * 32 + quad * 8);
                acc[nt] = __builtin_amdgcn_mfma_f32_16x16x32_bf16(af, bfr, acc[nt], 0, 0, 0);
            }
        }
    }

    #pragma unroll
    for (int nt = 0; nt < 4; ++nt) {
        int n = n0 + wc * 64 + nt * 16 + r16;
        float mbv = mb[n];
        #pragma unroll
        for (int reg = 0; reg < 4; ++reg) {
            int m = m0 + wr * 16 + quad * 4 + reg;
            float deg = (float)(row_ptr[m + 1] - row_ptr[m]);
            float v = acc[nt][reg] + deg * mbv
                    + node[(size_t)m * 256 + n] + pos[(size_t)(m & 511) * 256 + n];
            xo[(size_t)m * 256 + n] = v;
            xo_bf[(size_t)m * 256 + n] = (__bf16)v;
        }
    }
}

// ---------------------------------------------------------------------------
// FUSED per-layer tail v4 (proven, R5): direct frag-swizzled weight loads,
// 6 barriers, LDS only for o-tile / x1 / h. Bit-identical to v1 chain.
// ---------------------------------------------------------------------------
__global__ __launch_bounds__(256) void tail_fused(
    const __bf16* __restrict__ A,      // o_bf [8192 x 256]
    const __bf16* __restrict__ Wo,     // frag-swizzled [256 x 256]
    const float* __restrict__ ob,      // out_b [256]
    const float* __restrict__ res,     // x fp32 [8192 x 256]
    const float* __restrict__ g1, const float* __restrict__ b1,
    const __bf16* __restrict__ W1,     // frag-swizzled [512 x 256]
    const float* __restrict__ fb1,     // [512]
    const __bf16* __restrict__ W2,     // frag-swizzled [256 x 512]
    const float* __restrict__ fb2,     // [256]
    const float* __restrict__ g2, const float* __restrict__ b2,
    float* __restrict__ xo, __bf16* __restrict__ xo_bf, int wx32)
{
    __shared__ __bf16 As[16 * 264];    // 8.25 KB o-tile
    __shared__ __bf16 x1s[16 * 264];   // 8.25 KB
    __shared__ __bf16 hs[16 * 520];    // 16.25 KB
    __shared__ float redS[4][16], redQ[4][16];

    int tid = threadIdx.x;
    int m0 = blockIdx.x * 16;
    int w = tid >> 6, lane = tid & 63, quad = lane >> 4, r16 = lane & 15;

    // ---- stage o tile into LDS (reg-staged, padded rows) ----------------
    #pragma unroll
    for (int rpt = 0; rpt < 2; ++rpt) {
        int c = tid + rpt * 256;            // 512 chunks of 16B
        int row = c >> 5, cc = c & 31;
        bf16x8 v = *(const bf16x8*)(A + (size_t)(m0 + row) * 256 + cc * 8);
        *(bf16x8*)(&As[row * 264 + cc * 8]) = v;
    }
    __syncthreads();                        // B0

    // ---- stage A: T = o·Wo^T (K=256); wave w owns cols w*64..+63 --------
    f32x4 acc[4] = {};
    {
        const __bf16* wf = Wo + lane * 8;
        #pragma unroll
        for (int kc = 0; kc < 8; ++kc) {
            bf16x8 af = *(const bf16x8*)(&As[r16 * 264 + kc * 32 + quad * 8]);
            #pragma unroll
            for (int nt = 0; nt < 4; ++nt) {
                bf16x8 bfr = *(const bf16x8*)(wf + ((((w * 4 + nt) << 3) + kc) << 9));
                acc[nt] = __builtin_amdgcn_mfma_f32_16x16x32_bf16(af, bfr, acc[nt], 0, 0, 0);
            }
        }
    }

    // LN1: vv1 holds fp32 x1 (residual for LN2); bf16 copy goes to x1s.
    float vv1[4][4];
    {
        float ls[4], lq[4];
        #pragma unroll
        for (int reg = 0; reg < 4; ++reg) {
            int m = m0 + quad * 4 + reg;
            float s = 0.f, q = 0.f;
            #pragma unroll
            for (int nt = 0; nt < 4; ++nt) {
                int col = w * 64 + nt * 16 + r16;
                float val = acc[nt][reg] + ob[col] + res[(size_t)m * 256 + col];
                vv1[reg][nt] = val;
                s += val; q += val * val;
            }
            #pragma unroll
            for (int off = 1; off < 16; off <<= 1) {
                s += __shfl_xor(s, off);
                q += __shfl_xor(q, off);
            }
            ls[reg] = s; lq[reg] = q;
        }
        if (r16 == 0) {
            #pragma unroll
            for (int reg = 0; reg < 4; ++reg) {
                int r = quad * 4 + reg;
                redS[w][r] = ls[reg];
                redQ[w][r] = lq[reg];
            }
        }
        __syncthreads();                    // B1
        #pragma unroll
        for (int reg = 0; reg < 4; ++reg) {
            int r = quad * 4 + reg;
            float s = redS[0][r] + redS[1][r] + redS[2][r] + redS[3][r];
            float q = redQ[0][r] + redQ[1][r] + redQ[2][r] + redQ[3][r];
            float mu = s * (1.f / 256.f);
            float var = q * (1.f / 256.f) - mu * mu;
            float rstd = rsqrtf(var + 1e-5f);
            #pragma unroll
            for (int nt = 0; nt < 4; ++nt) {
                int col = w * 64 + nt * 16 + r16;
                float val = (vv1[reg][nt] - mu) * rstd * g1[col] + b1[col];
                vv1[reg][nt] = val;
                x1s[r * 264 + col] = (__bf16)val;
            }
        }
    }
    __syncthreads();                        // B2 (x1s visible to all waves)

    // ---- stage B: h = relu(x1·W1^T + b1); wave w owns cols w*128..+127 --
    f32x4 hacc[8] = {};
    {
        const __bf16* wf = W1 + lane * 8;
        #pragma unroll
        for (int kc = 0; kc < 8; ++kc) {
            bf16x8 af = *(const bf16x8*)(&x1s[r16 * 264 + kc * 32 + quad * 8]);
            #pragma unroll
            for (int nt = 0; nt < 8; ++nt) {
                bf16x8 bfr = *(const bf16x8*)(wf + ((((w * 8 + nt) << 3) + kc) << 9));
                hacc[nt] = __builtin_amdgcn_mfma_f32_16x16x32_bf16(af, bfr, hacc[nt], 0, 0, 0);
            }
        }
    }
    #pragma unroll
    for (int nt = 0; nt < 8; ++nt) {
        int col = w * 128 + nt * 16 + r16;
        float bb = fb1[col];
        #pragma unroll
        for (int reg = 0; reg < 4; ++reg) {
            float v = fmaxf(hacc[nt][reg] + bb, 0.f);
            hs[(quad * 4 + reg) * 520 + col] = (__bf16)v;
        }
    }
    __syncthreads();                        // B3

    // ---- stage C: T = h·W2^T (K=512); wave w owns cols w*64..+63 --------
    f32x4 cacc[4] = {};
    {
        const __bf16* wf = W2 + lane * 8;
        #pragma unroll
        for (int kc = 0; kc < 16; ++kc) {
            bf16x8 af = *(const bf16x8*)(&hs[r16 * 520 + kc * 32 + quad * 8]);
            #pragma unroll
            for (int nt = 0; nt < 4; ++nt) {
                bf16x8 bfr = *(const bf16x8*)(wf + ((((w * 4 + nt) << 4) + kc) << 9));
                cacc[nt] = __builtin_amdgcn_mfma_f32_16x16x32_bf16(af, bfr, cacc[nt], 0, 0, 0);
            }
        }
    }

    // LN2 epilogue: residual x1 comes straight from vv1 registers.
    {
        float vvc[4][4];
        float ls[4], lq[4];
        #pragma unroll
        for (int reg = 0; reg < 4; ++reg) {
            float s = 0.f, q = 0.f;
            #pragma unroll
            for (int nt = 0; nt < 4; ++nt) {
                int col = w * 64 + nt * 16 + r16;
                float val = cacc[nt][reg] + fb2[col] + vv1[reg][nt];
                vvc[reg][nt] = val;
                s += val; q += val * val;
            }
            #pragma unroll
            for (int off = 1; off < 16; off <<= 1) {
                s += __shfl_xor(s, off);
                q += __shfl_xor(q, off);
            }
            ls[reg] = s; lq[reg] = q;
        }
        __syncthreads();   // B4: protect redS/redQ reuse
        if (r16 == 0) {
            #pragma unroll
            for (int reg = 0; reg < 4; ++reg) {
                int r = quad * 4 + reg;
                redS[w][r] = ls[reg];
                redQ[w][r] = lq[reg];
            }
        }
        __syncthreads();                    // B5
        #pragma unroll
        for (int reg = 0; reg < 4; ++reg) {
            int r = quad * 4 + reg;
            int m = m0 + r;
            float s = redS[0][r] + redS[1][r] + redS[2][r] + redS[3][r];
            float q = redQ[0][r] + redQ[1][r] + redQ[2][r] + redQ[3][r];
            float mu = s * (1.f / 256.f);
            float var = q * (1.f / 256.f) - mu * mu;
            float rstd = rsqrtf(var + 1e-5f);
            #pragma unroll
            for (int nt = 0; nt < 4; ++nt) {
                int col = w * 64 + nt * 16 + r16;
                float val = (vvc[reg][nt] - mu) * rstd * g2[col] + b2[col];
                if (wx32) xo[(size_t)m * 256 + col] = val;
                xo_bf[(size_t)m * 256 + col] = (__bf16)val;
            }
        }
    }
}

// ---------------------------------------------------------------------------
// MFMA flash attention v7 (proven, R7): QBLK=128, grid (4,128). Each wave
// owns TWO Q-tiles sharing ONE K-fragment prefetch set; whole-V^T staged
// once; ONE barrier per block.
// ---------------------------------------------------------------------------
#define VSL 520
#define PS 72

__global__ __launch_bounds__(256) void attn_mfma_kernel(
    const __bf16* __restrict__ qkv, __bf16* __restrict__ o)
{
    __shared__ __bf16 Vt[32 * VSL];        // 33.3 KB, V^T for all 512 keys
    __shared__ __bf16 Ps[4][2][16 * PS];   // 18.4 KB, per-wave per-qtile P

    int tid  = threadIdx.x;
    int w    = tid >> 6, lane = tid & 63;
    int quad = lane >> 4, r16 = lane & 15;
    int qt = blockIdx.x;            // 0..3
    int bh = blockIdx.y;            // 0..127
    int b = bh >> 3, h = bh & 7;
    int base = b * S_;
    int q0 = qt * 128;

    bf16x8 qa[2];
    #pragma unroll
    for (int u = 0; u < 2; ++u)
        qa[u] = *(const bf16x8*)(
            qkv + (size_t)(base + q0 + u * 64 + w * 16 + r16) * 768 + h * 32 + quad * 8);

    int kp  = tid & 31;
    int cch = (tid >> 5) & 3;
    int jh  = tid >> 7;
    const __bf16* vbase = qkv + (size_t)base * 768 + 512 + h * 32 + cch * 8;
    const __bf16* kbase = qkv + (size_t)base * 768 + 256 + h * 32 + quad * 8;

    // ---- stage entire V^T once ------------------------------------------
    #pragma unroll
    for (int kt2 = 0; kt2 < 8; kt2 += 2) {
        bf16x8 a0 = *(const bf16x8*)(vbase + (size_t)(kt2 * 64 + 2 * kp) * 768);
        bf16x8 a1 = *(const bf16x8*)(vbase + (size_t)(kt2 * 64 + 2 * kp + 1) * 768);
        bf16x8 b0 = *(const bf16x8*)(vbase + (size_t)((kt2 + 1) * 64 + 2 * kp) * 768);
        bf16x8 b1 = *(const bf16x8*)(vbase + (size_t)((kt2 + 1) * 64 + 2 * kp + 1) * 768);
        #pragma unroll
        for (int j = 0; j < 4; ++j) {
            int jj = jh * 4 + j;
            int d = cch * 8 + jj;
            union { __bf16 hh[2]; unsigned int u; } p0, p1;
            p0.hh[0] = a0[jj]; p0.hh[1] = a1[jj];
            p1.hh[0] = b0[jj]; p1.hh[1] = b1[jj];
            *(unsigned int*)(&Vt[d * VSL + kt2 * 64 + 2 * kp]) = p0.u;
            *(unsigned int*)(&Vt[d * VSL + (kt2 + 1) * 64 + 2 * kp]) = p1.u;
        }
    }

    // K prefetch for kt=0 (shared by both Q-tiles)
    bf16x8 kb[4], kbn[4];
    #pragma unroll
    for (int t = 0; t < 4; ++t)
        kbn[t] = *(const bf16x8*)(kbase + (size_t)(t * 16 + r16) * 768);

    f32x4 oacc[2][2] = {};
    float l_i[2][4] = {};

    __syncthreads();   // single barrier: Vt visible to all waves

    for (int kt = 0; kt < 8; ++kt) {
        #pragma unroll
        for (int t = 0; t < 4; ++t) kb[t] = kbn[t];
        if (kt < 7) {
            int off = (kt + 1) * 64;
            #pragma unroll
            for (int t = 0; t < 4; ++t)
                kbn[t] = *(const bf16x8*)(kbase + (size_t)(off + t * 16 + r16) * 768);
        }

        // QK^T: 8 independent MFMAs (2 Q-tiles x 4 key-subtiles), one kb set
        f32x4 s[2][4];
        #pragma unroll
        for (int u = 0; u < 2; ++u)
            #pragma unroll
            for (int t = 0; t < 4; ++t)
                s[u][t] = __builtin_amdgcn_mfma_f32_16x16x32_bf16(
                    qa[u], kb[t], (f32x4){0.f, 0.f, 0.f, 0.f}, 0, 0, 0);

        #pragma unroll
        for (int u = 0; u < 2; ++u) {
            #pragma unroll
            for (int r = 0; r < 4; ++r) {
                float p0 = __expf(s[u][0][r]), p1 = __expf(s[u][1][r]);
                float p2 = __expf(s[u][2][r]), p3 = __expf(s[u][3][r]);
                l_i[u][r] += (p0 + p1) + (p2 + p3);
                __bf16* pw = &Ps[w][u][(quad * 4 + r) * PS + r16];
                pw[0]  = (__bf16)p0;
                pw[16] = (__bf16)p1;
                pw[32] = (__bf16)p2;
                pw[48] = (__bf16)p3;
            }
        }

        // PV: 8 MFMAs (2 Q-tiles x 2 key-chunks x 2 d-halves), shared Vt
        #pragma unroll
        for (int u = 0; u < 2; ++u) {
            #pragma unroll
            for (int c = 0; c < 2; ++c) {
                bf16x8 pa  = *(const bf16x8*)(&Ps[w][u][r16 * PS + c * 32 + quad * 8]);
                bf16x8 vb0 = *(const bf16x8*)(&Vt[r16 * VSL + kt * 64 + c * 32 + quad * 8]);
                bf16x8 vb1 = *(const bf16x8*)(&Vt[(16 + r16) * VSL + kt * 64 + c * 32 + quad * 8]);
                oacc[u][0] = __builtin_amdgcn_mfma_f32_16x16x32_bf16(pa, vb0, oacc[u][0], 0, 0, 0);
                oacc[u][1] = __builtin_amdgcn_mfma_f32_16x16x32_bf16(pa, vb1, oacc[u][1], 0, 0, 0);
            }
        }
    }

    #pragma unroll
    for (int u = 0; u < 2; ++u) {
        #pragma unroll
        for (int r = 0; r < 4; ++r) {
            float ls = l_i[u][r];
            #pragma unroll
            for (int off = 1; off < 16; off <<= 1) ls += __shfl_xor(ls, off);
            float inv = 1.0f / ls;
            int q = base + q0 + u * 64 + w * 16 + quad * 4 + r;
            __bf16* op = o + (size_t)q * 256 + h * 32;
            op[r16]      = (__bf16)(oacc[u][0][r] * inv);
            op[16 + r16] = (__bf16)(oacc[u][1][r] * inv);
        }
    }
}

// ---------------------------------------------------------------------------
// MFMA edge predictions.
// ---------------------------------------------------------------------------
#define PP 264

__global__ __launch_bounds__(256) void pred_mfma(
    const __bf16* __restrict__ xbf, const int* __restrict__ ep,
    const int* __restrict__ en, const __bf16* __restrict__ Wp,
    const float* __restrict__ pe_b, const float* __restrict__ pt_b,
    float* __restrict__ out)
{
    __shared__ __bf16 P[4][16 * PP];   // 33 KB
    int tid = threadIdx.x;
    int w = tid >> 6, lane = tid & 63, quad = lane >> 4, r16 = lane & 15;
    int isPos = blockIdx.x < 512;
    int e0 = (blockIdx.x & 511) * 64 + w * 16;
    const int* epair = isPos ? ep : en;

    int half = lane >> 5;
    int col = (lane & 31) * 8;
    #pragma unroll
    for (int j = 0; j < 8; ++j) {
        int je = j * 2 + half;
        int e = e0 + je;
        int a = epair[2 * e], c = epair[2 * e + 1];
        bf16x8 av = *(const bf16x8*)(xbf + (size_t)a * 256 + col);
        bf16x8 cv = *(const bf16x8*)(xbf + (size_t)c * 256 + col);
        bf16x8 pv;
        #pragma unroll
        for (int t = 0; t < 8; ++t)
            pv[t] = (__bf16)((float)av[t] * (float)cv[t]);
        *(bf16x8*)(&P[w][je * PP + col]) = pv;
    }
    __syncthreads();

    f32x4 acc1 = {0.f, 0.f, 0.f, 0.f};
    f32x4 acc2 = {0.f, 0.f, 0.f, 0.f};
    #pragma unroll
    for (int k0 = 0; k0 < 256; k0 += 32) {
        bf16x8 af = *(const bf16x8*)(&P[w][r16 * PP + k0 + quad * 8]);
        bf16x8 b2 = *(const bf16x8*)(Wp + (size_t)(16 + r16) * 256 + k0 + quad * 8);
        acc2 = __builtin_amdgcn_mfma_f32_16x16x32_bf16(af, b2, acc2, 0, 0, 0);
        if (isPos) {
            bf16x8 b1 = *(const bf16x8*)(Wp + (size_t)r16 * 256 + k0 + quad * 8);
            acc1 = __builtin_amdgcn_mfma_f32_16x16x32_bf16(af, b1, acc1, 0, 0, 0);
        }
    }

    float* pred_pos = out;
    float* pred_neg = out + NE_;
    float* pred_type = out + 2 * NE_;
    float peb = pe_b[0];
    if (isPos) {
        float ptbv = pt_b[r16];
        #pragma unroll
        for (int reg = 0; reg < 4; ++reg) {
            int e = e0 + quad * 4 + reg;
            pred_type[(size_t)e * 16 + r16] = acc1[reg] + ptbv;
        }
        if (r16 == 0) {
            #pragma unroll
            for (int reg = 0; reg < 4; ++reg)
                pred_pos[e0 + quad * 4 + reg] = acc2[reg] + peb;
        }
    } else {
        if (r16 == 0) {
            #pragma unroll
            for (int reg = 0; reg < 4; ++reg)
                pred_neg[e0 + quad * 4 + reg] = acc2[reg] + peb;
        }
    }
}

// ---------------------------------------------------------------------------
extern "C" void kernel_launch(void* const* d_in, const int* in_sizes, int n_in,
                              void* d_out, int out_size, void* d_ws, size_t ws_size,
                              hipStream_t stream)
{
    const float* node_emb  = (const float*)d_in[0];
    const float* edge_emb  = (const float*)d_in[1];
    const int*   incidence = (const int*)d_in[2];
    const int*   edges_neg = (const int*)d_in[4];
    const int*   edges_pos = (const int*)d_in[5];
    const float* msg_w1    = (const float*)d_in[6];
    const float* msg_w2    = (const float*)d_in[7];
    const float* msg_b     = (const float*)d_in[8];
    const float* pos_table = (const float*)d_in[9];
    const float* in_proj_w = (const float*)d_in[10];
    const float* in_proj_b = (const float*)d_in[11];
    const float* out_w     = (const float*)d_in[12];
    const float* out_b     = (const float*)d_in[13];
    const float* ln1_g     = (const float*)d_in[14];
    const float* ln1_b     = (const float*)d_in[15];
    const float* ff_w1     = (const float*)d_in[16];
    const float* ff_b1     = (const float*)d_in[17];
    const float* ff_w2     = (const float*)d_in[18];
    const float* ff_b2     = (const float*)d_in[19];
    const float* ln2_g     = (const float*)d_in[20];
    const float* ln2_b     = (const float*)d_in[21];
    const float* pe_w      = (const float*)d_in[22];
    const float* pe_b      = (const float*)d_in[23];
    const float* pt_w      = (const float*)d_in[24];
    const float* pt_b      = (const float*)d_in[25];

    // workspace layout (~48.4 MB)
    float*  x       = (float*)d_ws;                       // N*D fp32 (8 MB)
    __bf16* x_bf    = (__bf16*)(x + (size_t)N_ * D_);     // N*D bf16 (4 MB)
    __bf16* ipwf_bf = x_bf + (size_t)N_ * D_;             // 4*768*256 swizzled (1.5 MB)
    __bf16* ow_bf   = ipwf_bf + 786432;                   // 4*256*256 (0.5 MB)
    __bf16* fw1_bf  = ow_bf + 262144;                     // 4*512*256 (1 MB)
    __bf16* fw2_bf  = fw1_bf + 524288;                    // 4*256*512 (1 MB)
    __bf16* wcat_bf = fw2_bf + 524288;                    // 256*512  (0.25 MB)
    __bf16* wp_bf   = wcat_bf + 131072;                   // 32*256   (16 KB)
    float*  ipb_s   = (float*)(wp_bf + 8192);             // 4*768 fp32 (12 KB)
    float*  scratch = ipb_s + 3072;                       // 24 MB union:
    int*    cnt     = (int*)scratch;                      // 8192
    int*    row_ptr = cnt + 8192;                         // 8193
    int*    ofs     = row_ptr + 8200;                     // 8192
    int*    elist   = ofs + 8192;                         // 65536
    __bf16* qkv_bf = (__bf16*)scratch;                    // N*768 (12 MB)
    __bf16* o_bf   = qkv_bf + (size_t)N_ * 768;           // N*D   (4 MB)
    __bf16* G_bf   = (__bf16*)(scratch + 6291456);        // +24 MB: N*512 bf16 (8 MB)

    // 0. weight conversions (q pre-scaled; ipw/ow/fw1/fw2 fragment-swizzled)
    convert_all<<<2195, 256, 0, stream>>>(
        in_proj_w, ipwf_bf, out_w, ow_bf, ff_w1, fw1_bf, ff_w2, fw2_bf,
        msg_w1, msg_w2, wcat_bf, pt_w, pe_w, wp_bf, in_proj_b, ipb_s, cnt);

    // 1. CSR build over destination nodes (incidence[0])
    hist_kernel<<<E_ / 256, 256, 0, stream>>>(incidence, cnt);
    scan_kernel<<<1, 256, 0, stream>>>(cnt, row_ptr, ofs);
    fill_kernel<<<E_ / 256, 256, 0, stream>>>(incidence, ofs, elist);

    // 2. gather-sum -> G_bf (atomics-free); agreg GEMM fused with
    //    x = node + pos + agreg (32-row tiles, 512 blocks)
    csr_gather<<<N_ / 4, 256, 0, stream>>>(
        node_emb, edge_emb, incidence, row_ptr, elist, G_bf);
    agreg_gemm<<<dim3(2, N_ / 32), 256, 0, stream>>>(
        G_bf, wcat_bf, row_ptr, msg_b, node_emb, pos_table, x, x_bf);

    // 3. transformer layers: QKV (frag, 1-barrier) -> attention -> fused tail
    for (int li = 0; li < L_; ++li) {
        qkv_frag<<<dim3(768 / 128, N_ / 64), 256, 0, stream>>>(
            x_bf, ipwf_bf + (size_t)li * 196608, ipb_s + li * 768, qkv_bf);
        attn_mfma_kernel<<<dim3(S_ / 128, B_ * H_), 256, 0, stream>>>(qkv_bf, o_bf);
        tail_fused<<<N_ / 16, 256, 0, stream>>>(
            o_bf, ow_bf + (size_t)li * 65536, out_b + li * 256,
            x, ln1_g + li * 256, ln1_b + li * 256,
            fw1_bf + (size_t)li * 131072, ff_b1 + li * 512,
            fw2_bf + (size_t)li * 131072, ff_b2 + li * 256,
            ln2_g + li * 256, ln2_b + li * 256,
            x, x_bf, li == L_ - 1 ? 0 : 1);
    }

    // 4. MFMA edge predictions
    pred_mfma<<<1024, 256, 0, stream>>>(
        x_bf, edges_pos, edges_neg, wp_bf, pe_b, pt_b, (float*)d_out);
}

// Round 11
// 398.526 us; speedup vs baseline: 1.0165x; 1.0165x over previous
//
#include <hip/hip_runtime.h>
#include <hip/hip_bf16.h>

// Shapes (fixed by the reference)
#define B_  16
#define S_  512
#define D_  256
#define H_  8
#define L_  4
#define K_  16
#define N_  (B_ * S_)     // 8192
#define E_  65536
#define NE_ 32768
#define DFF_ 512
#define HD_ 32

typedef __attribute__((ext_vector_type(8))) __bf16 bf16x8;
typedef __attribute__((ext_vector_type(4))) __bf16 bf16x4;
typedef __attribute__((ext_vector_type(4))) float f32x4;

// async global->LDS, 16B per lane. LDS dest must be lane-contiguous (base+lane*16).
__device__ __forceinline__ void gl2lds16(const void* g, void* l) {
    __builtin_amdgcn_global_load_lds(
        (const __attribute__((address_space(1))) unsigned int*)g,
        (__attribute__((address_space(3))) unsigned int*)l, 16, 0, 0);
}

#define QSCALE 0.17677669529663688f   // 1/sqrt(32), folded into wq/bq

// ---------------------------------------------------------------------------
// Combined fp32 -> bf16 conversion for weights (1 launch) + cnt zeroing.
// ow/fw1/fw2 are stored MFMA-FRAGMENT-SWIZZLED: fragment (rg, kc) holds, at
// lane l, elements W[rg*16 + (l&15)][kc*32 + (l>>4)*8 .. +8], flat address
// layer_base + (rg*KC + kc)*512 + l*8. A wave's fragment load is then one
// contiguous 1 KB read (perfect coalescing, no LDS staging needed).
// in_proj stays LINEAR (the staged qkv GEMM wants gl2lds16-able rows).
// ---------------------------------------------------------------------------
__global__ __launch_bounds__(256) void convert_all(
    const float* __restrict__ ipw, __bf16* __restrict__ ipw_bf,
    const float* __restrict__ ow,  __bf16* __restrict__ ow_bf,
    const float* __restrict__ fw1, __bf16* __restrict__ fw1_bf,
    const float* __restrict__ fw2, __bf16* __restrict__ fw2_bf,
    const float* __restrict__ mw1, const float* __restrict__ mw2,
    __bf16* __restrict__ wcat_bf,
    const float* __restrict__ ptw, const float* __restrict__ pew,
    __bf16* __restrict__ wp_bf,
    const float* __restrict__ ipb, float* __restrict__ ipb_s,
    int* __restrict__ cnt)
{
    int blk = blockIdx.x;
    if (blk < 768) {
        // in_proj_w with q-row scaling (linear layout)
        size_t i = ((size_t)blk * 256 + threadIdx.x) * 4;
        int row = (int)((i >> 8) % 768);
        float sc = (row < 256) ? QSCALE : 1.0f;
        float4 v = *(const float4*)(ipw + i);
        bf16x4 o = {(__bf16)(v.x * sc), (__bf16)(v.y * sc),
                    (__bf16)(v.z * sc), (__bf16)(v.w * sc)};
        *(bf16x4*)(ipw_bf + i) = o;
    } else if (blk < 2048) {
        // ow / fw1 / fw2 -> fragment-swizzled bf16
        const float* src; __bf16* dst; int base;
        if      (blk < 1024)  { src = ow;   dst = ow_bf;   base = blk - 768; }
        else if (blk < 1536)  { src = fw1;  dst = fw1_bf;  base = blk - 1024; }
        else                  { src = fw2;  dst = fw2_bf;  base = blk - 1536; }
        size_t i = ((size_t)base * 256 + threadIdx.x) * 4;
        float4 v = *(const float4*)(src + i);
        int layer, row, col, kchunks; size_t lstride;
        if (blk < 1024) {            // ow: 4 x [256 x 256]
            layer = (int)(i >> 16); int idx = (int)(i & 65535);
            row = idx >> 8; col = idx & 255; kchunks = 8; lstride = 65536;
        } else if (blk < 1536) {     // fw1: 4 x [512 x 256]
            layer = (int)(i >> 17); int idx = (int)(i & 131071);
            row = idx >> 8; col = idx & 255; kchunks = 8; lstride = 131072;
        } else {                     // fw2: 4 x [256 x 512]
            layer = (int)(i >> 17); int idx = (int)(i & 131071);
            row = idx >> 9; col = idx & 511; kchunks = 16; lstride = 131072;
        }
        size_t dsti = (size_t)layer * lstride
                    + (size_t)((((row >> 4) * kchunks + (col >> 5)) << 9)
                               + ((col & 31) >> 3) * 128 + (row & 15) * 8 + (col & 7));
        bf16x4 o = {(__bf16)v.x, (__bf16)v.y, (__bf16)v.z, (__bf16)v.w};
        *(bf16x4*)(dst + dsti) = o;
    } else if (blk < 2176) {
        int isw2 = blk >= 2112;
        int base = blk - (isw2 ? 2112 : 2048);
        const float* src = isw2 ? mw2 : mw1;
        size_t i = ((size_t)base * 256 + threadIdx.x) * 4;   // elem in [256x256]
        int row = i >> 8, col = i & 255;
        float4 v = *(const float4*)(src + i);
        bf16x4 o = {(__bf16)v.x, (__bf16)v.y, (__bf16)v.z, (__bf16)v.w};
        *(bf16x4*)(wcat_bf + (size_t)row * 512 + (isw2 ? 256 : 0) + col) = o;
    } else if (blk < 2184) {
        int base = blk - 2176;
        size_t i = ((size_t)base * 256 + threadIdx.x) * 4;
        int row = i >> 8, col = i & 255;
        float4 v = make_float4(0.f, 0.f, 0.f, 0.f);
        if (row < 16)       v = *(const float4*)(ptw + row * 256 + col);
        else if (row == 16) v = *(const float4*)(pew + col);
        bf16x4 o = {(__bf16)v.x, (__bf16)v.y, (__bf16)v.z, (__bf16)v.w};
        *(bf16x4*)(wp_bf + i) = o;
    } else if (blk < 2187) {
        // scaled in_proj bias: 4*768 = 3072 floats, 3 blocks
        int base = blk - 2184;
        size_t i = ((size_t)base * 256 + threadIdx.x) * 4;
        if (i < 3072) {
            float sc = ((i % 768) < 256) ? QSCALE : 1.0f;
            float4 v = *(const float4*)(ipb + i);
            *(float4*)(ipb_s + i) = make_float4(v.x * sc, v.y * sc, v.z * sc, v.w * sc);
        }
    } else {
        int base = blk - 2187;
        int4* p = (int4*)(cnt + ((size_t)base * 256 + threadIdx.x) * 4);
        *p = make_int4(0, 0, 0, 0);
    }
}

// ---------------------------------------------------------------------------
// CSR build over destination nodes: histogram -> scan -> bucket fill.
// ---------------------------------------------------------------------------
__global__ __launch_bounds__(256) void hist_kernel(
    const int* __restrict__ inc, int* __restrict__ cnt)
{
    int e = blockIdx.x * 256 + threadIdx.x;
    atomicAdd(&cnt[inc[e]], 1);
}

__global__ __launch_bounds__(256) void scan_kernel(
    const int* __restrict__ cnt, int* __restrict__ row_ptr, int* __restrict__ ofs)
{
    __shared__ int part[256];
    int t = threadIdx.x;
    int base = t * 32, sum = 0;
    int local[32];
    #pragma unroll
    for (int j = 0; j < 32; ++j) { local[j] = cnt[base + j]; sum += local[j]; }
    part[t] = sum;
    __syncthreads();
    #pragma unroll
    for (int off = 1; off < 256; off <<= 1) {
        int other = (t >= off) ? part[t - off] : 0;
        __syncthreads();
        part[t] += other;
        __syncthreads();
    }
    int run = part[t] - sum;   // exclusive prefix
    for (int j = 0; j < 32; ++j) {
        row_ptr[base + j] = run;
        ofs[base + j] = run;
        run += local[j];
    }
    if (t == 255) row_ptr[8192] = run;
}

__global__ __launch_bounds__(256) void fill_kernel(
    const int* __restrict__ inc, int* __restrict__ ofs, int* __restrict__ elist)
{
    int e = blockIdx.x * 256 + threadIdx.x;
    int pos = atomicAdd(&ofs[inc[e]], 1);
    elist[pos] = e;
}

// ---------------------------------------------------------------------------
// CSR gather: G_bf[n][0:256] = sum node[inc1[e]], G_bf[n][256:512] = sum
// edge[e]. One wave per node, fp32 accumulate, 2-edge unroll for MLP.
// ---------------------------------------------------------------------------
__global__ __launch_bounds__(256) void csr_gather(
    const float* __restrict__ node, const float* __restrict__ edge,
    const int* __restrict__ inc, const int* __restrict__ row_ptr,
    const int* __restrict__ elist, __bf16* __restrict__ G)
{
    int n = blockIdx.x * 4 + (threadIdx.x >> 6);
    int lane = threadIdx.x & 63;
    int s = row_ptr[n], epos = row_ptr[n + 1];
    float4 an = {0.f, 0.f, 0.f, 0.f}, ae = {0.f, 0.f, 0.f, 0.f};
    int i = s;
    for (; i + 2 <= epos; i += 2) {
        int e0 = elist[i], e1 = elist[i + 1];
        int s0 = inc[E_ + e0], s1 = inc[E_ + e1];
        float4 nv0 = *(const float4*)(node + (size_t)s0 * 256 + lane * 4);
        float4 ev0 = *(const float4*)(edge + (size_t)e0 * 256 + lane * 4);
        float4 nv1 = *(const float4*)(node + (size_t)s1 * 256 + lane * 4);
        float4 ev1 = *(const float4*)(edge + (size_t)e1 * 256 + lane * 4);
        an.x += nv0.x + nv1.x; an.y += nv0.y + nv1.y;
        an.z += nv0.z + nv1.z; an.w += nv0.w + nv1.w;
        ae.x += ev0.x + ev1.x; ae.y += ev0.y + ev1.y;
        ae.z += ev0.z + ev1.z; ae.w += ev0.w + ev1.w;
    }
    if (i < epos) {
        int e0 = elist[i];
        int s0 = inc[E_ + e0];
        float4 nv0 = *(const float4*)(node + (size_t)s0 * 256 + lane * 4);
        float4 ev0 = *(const float4*)(edge + (size_t)e0 * 256 + lane * 4);
        an.x += nv0.x; an.y += nv0.y; an.z += nv0.z; an.w += nv0.w;
        ae.x += ev0.x; ae.y += ev0.y; ae.z += ev0.z; ae.w += ev0.w;
    }
    __bf16* g = G + (size_t)n * 512 + lane * 4;
    bf16x4 bn = {(__bf16)an.x, (__bf16)an.y, (__bf16)an.z, (__bf16)an.w};
    bf16x4 be = {(__bf16)ae.x, (__bf16)ae.y, (__bf16)ae.z, (__bf16)ae.w};
    *(bf16x4*)g = bn;
    *(bf16x4*)(g + 256) = be;
}

// ---------------------------------------------------------------------------
// bf16 MFMA GEMM: C[M,N] = A[M,K]·B[N,K]^T + bias (+relu), OutT epilogue cast.
// 64x128 tile, BK=64 via two stride-32 LDS regions per operand. (QKV proj)
// Proven structure: gl2lds16 staging + implicit multi-block overlap.
// ---------------------------------------------------------------------------
template <typename OutT>
__global__ __launch_bounds__(256) void gemm_mfma(
    const __bf16* __restrict__ A, const __bf16* __restrict__ Bw,
    const float* __restrict__ bias, OutT* __restrict__ C,
    int M, int N, int Kd, int relu)
{
    __shared__ __bf16 As0[64 * 32], As1[64 * 32];
    __shared__ __bf16 Bs0[128 * 32], Bs1[128 * 32];
    int tid = threadIdx.x;
    int m0 = blockIdx.y * 64, n0 = blockIdx.x * 128;
    int w = tid >> 6, lane = tid & 63, quad = lane >> 4, r16 = lane & 15;
    int wr = w >> 1, wc = w & 1;

    int lr = tid >> 2, lc = (tid & 3) * 8;
    const __bf16* ag  = A  + (size_t)(m0 + lr) * Kd + lc;
    const __bf16* bg0 = Bw + (size_t)(n0 + lr) * Kd + lc;
    const __bf16* bg1 = bg0 + (size_t)64 * Kd;

    f32x4 acc[2][4] = {};

    for (int k0 = 0; k0 < Kd; k0 += 64) {
        __syncthreads();
        gl2lds16(ag + k0,        As0 + tid * 8);
        gl2lds16(ag + k0 + 32,   As1 + tid * 8);
        gl2lds16(bg0 + k0,       Bs0 + tid * 8);
        gl2lds16(bg1 + k0,       Bs0 + 2048 + tid * 8);
        gl2lds16(bg0 + k0 + 32,  Bs1 + tid * 8);
        gl2lds16(bg1 + k0 + 32,  Bs1 + 2048 + tid * 8);
        __syncthreads();

        #pragma unroll
        for (int kh = 0; kh < 2; ++kh) {
            const __bf16* Asr = kh ? As1 : As0;
            const __bf16* Bsr = kh ? Bs1 : Bs0;
            bf16x8 af[2], bfr[4];
            #pragma unroll
            for (int mt = 0; mt < 2; ++mt)
                af[mt] = *(const bf16x8*)(Asr + (wr * 32 + mt * 16 + r16) * 32 + quad * 8);
            #pragma unroll
            for (int nt = 0; nt < 4; ++nt)
                bfr[nt] = *(const bf16x8*)(Bsr + (wc * 64 + nt * 16 + r16) * 32 + quad * 8);
            #pragma unroll
            for (int mt = 0; mt < 2; ++mt)
                #pragma unroll
                for (int nt = 0; nt < 4; ++nt)
                    acc[mt][nt] = __builtin_amdgcn_mfma_f32_16x16x32_bf16(
                        af[mt], bfr[nt], acc[mt][nt], 0, 0, 0);
        }
    }

    #pragma unroll
    for (int nt = 0; nt < 4; ++nt) {
        int n = n0 + wc * 64 + nt * 16 + r16;
        float bv = bias[n];
        #pragma unroll
        for (int mt = 0; mt < 2; ++mt) {
            #pragma unroll
            for (int reg = 0; reg < 4; ++reg) {
                int m = m0 + wr * 32 + mt * 16 + quad * 4 + reg;
                float v = acc[mt][nt][reg] + bv;
                if (relu) v = fmaxf(v, 0.f);
                C[(size_t)m * N + n] = (OutT)v;
            }
        }
    }
}

// ---------------------------------------------------------------------------
// agreg GEMM v2 (32-row tiles, grid (2,256) = 512 blocks for 2 blocks/CU):
// x[m,n] = G_bf[m,:]·wcat[n,:] + deg(m)*msg_b[n] + node[m,n] + pos[m%512,n]
// ---------------------------------------------------------------------------
__global__ __launch_bounds__(256) void agreg_gemm(
    const __bf16* __restrict__ G, const __bf16* __restrict__ Wc,
    const int* __restrict__ row_ptr, const float* __restrict__ mb,
    const float* __restrict__ node, const float* __restrict__ pos,
    float* __restrict__ xo, __bf16* __restrict__ xo_bf)
{
    __shared__ __bf16 As0[32 * 32], As1[32 * 32];      // 2 KB each
    __shared__ __bf16 Bs0[128 * 32], Bs1[128 * 32];    // 8 KB each
    int tid = threadIdx.x;
    int m0 = blockIdx.y * 32, n0 = blockIdx.x * 128;
    int w = tid >> 6, lane = tid & 63, quad = lane >> 4, r16 = lane & 15;
    int wr = w >> 1, wc = w & 1;

    int lr = tid >> 2, lc = (tid & 3) * 8;
    const __bf16* ag  = G  + (size_t)(m0 + (tid >> 2 & 31)) * 512 + lc;
    const __bf16* bg0 = Wc + (size_t)(n0 + lr) * 512 + lc;
    const __bf16* bg1 = bg0 + (size_t)64 * 512;

    f32x4 acc[4] = {};   // [nt], wave = 16 rows x 64 cols

    for (int k0 = 0; k0 < 512; k0 += 64) {
        __syncthreads();
        if (tid < 128) {
            gl2lds16(ag + k0,      As0 + tid * 8);
            gl2lds16(ag + k0 + 32, As1 + tid * 8);
        }
        gl2lds16(bg0 + k0,       Bs0 + tid * 8);
        gl2lds16(bg1 + k0,       Bs0 + 2048 + tid * 8);
        gl2lds16(bg0 + k0 + 32,  Bs1 + tid * 8);
        gl2lds16(bg1 + k0 + 32,  Bs1 + 2048 + tid * 8);
        __syncthreads();

        #pragma unroll
        for (int kh = 0; kh < 2; ++kh) {
            const __bf16* Asr = kh ? As1 : As0;
            const __bf16* Bsr = kh ? Bs1 : Bs0;
            bf16x8 af = *(const bf16x8*)(Asr + (wr * 16 + r16) * 32 + quad * 8);
            #pragma unroll
            for (int nt = 0; nt < 4; ++nt) {
                bf16x8 bfr = *(const bf16x8*)(Bsr + (wc * 64 + nt * 16 + r16) * 32 + quad * 8);
                acc[nt] = __builtin_amdgcn_mfma_f32_16x16x32_bf16(af, bfr, acc[nt], 0, 0, 0);
            }
        }
    }

    #pragma unroll
    for (int nt = 0; nt < 4; ++nt) {
        int n = n0 + wc * 64 + nt * 16 + r16;
        float mbv = mb[n];
        #pragma unroll
        for (int reg = 0; reg < 4; ++reg) {
            int m = m0 + wr * 16 + quad * 4 + reg;
            float deg = (float)(row_ptr[m + 1] - row_ptr[m]);
            float v = acc[nt][reg] + deg * mbv
                    + node[(size_t)m * 256 + n] + pos[(size_t)(m & 511) * 256 + n];
            xo[(size_t)m * 256 + n] = v;
            xo_bf[(size_t)m * 256 + n] = (__bf16)v;
        }
    }
}

// ---------------------------------------------------------------------------
// FUSED per-layer tail v4 (proven, R5): direct frag-swizzled weight loads,
// 6 barriers, LDS only for o-tile / x1 / h. Bit-identical to v1 chain.
// ---------------------------------------------------------------------------
__global__ __launch_bounds__(256) void tail_fused(
    const __bf16* __restrict__ A,      // o_bf [8192 x 256]
    const __bf16* __restrict__ Wo,     // frag-swizzled [256 x 256]
    const float* __restrict__ ob,      // out_b [256]
    const float* __restrict__ res,     // x fp32 [8192 x 256]
    const float* __restrict__ g1, const float* __restrict__ b1,
    const __bf16* __restrict__ W1,     // frag-swizzled [512 x 256]
    const float* __restrict__ fb1,     // [512]
    const __bf16* __restrict__ W2,     // frag-swizzled [256 x 512]
    const float* __restrict__ fb2,     // [256]
    const float* __restrict__ g2, const float* __restrict__ b2,
    float* __restrict__ xo, __bf16* __restrict__ xo_bf, int wx32)
{
    __shared__ __bf16 As[16 * 264];    // 8.25 KB o-tile
    __shared__ __bf16 x1s[16 * 264];   // 8.25 KB
    __shared__ __bf16 hs[16 * 520];    // 16.25 KB
    __shared__ float redS[4][16], redQ[4][16];

    int tid = threadIdx.x;
    int m0 = blockIdx.x * 16;
    int w = tid >> 6, lane = tid & 63, quad = lane >> 4, r16 = lane & 15;

    // ---- stage o tile into LDS (reg-staged, padded rows) ----------------
    #pragma unroll
    for (int rpt = 0; rpt < 2; ++rpt) {
        int c = tid + rpt * 256;            // 512 chunks of 16B
        int row = c >> 5, cc = c & 31;
        bf16x8 v = *(const bf16x8*)(A + (size_t)(m0 + row) * 256 + cc * 8);
        *(bf16x8*)(&As[row * 264 + cc * 8]) = v;
    }
    __syncthreads();                        // B0

    // ---- stage A: T = o·Wo^T (K=256); wave w owns cols w*64..+63 --------
    f32x4 acc[4] = {};
    {
        const __bf16* wf = Wo + lane * 8;
        #pragma unroll
        for (int kc = 0; kc < 8; ++kc) {
            bf16x8 af = *(const bf16x8*)(&As[r16 * 264 + kc * 32 + quad * 8]);
            #pragma unroll
            for (int nt = 0; nt < 4; ++nt) {
                bf16x8 bfr = *(const bf16x8*)(wf + ((((w * 4 + nt) << 3) + kc) << 9));
                acc[nt] = __builtin_amdgcn_mfma_f32_16x16x32_bf16(af, bfr, acc[nt], 0, 0, 0);
            }
        }
    }

    // LN1: vv1 holds fp32 x1 (residual for LN2); bf16 copy goes to x1s.
    float vv1[4][4];
    {
        float ls[4], lq[4];
        #pragma unroll
        for (int reg = 0; reg < 4; ++reg) {
            int m = m0 + quad * 4 + reg;
            float s = 0.f, q = 0.f;
            #pragma unroll
            for (int nt = 0; nt < 4; ++nt) {
                int col = w * 64 + nt * 16 + r16;
                float val = acc[nt][reg] + ob[col] + res[(size_t)m * 256 + col];
                vv1[reg][nt] = val;
                s += val; q += val * val;
            }
            #pragma unroll
            for (int off = 1; off < 16; off <<= 1) {
                s += __shfl_xor(s, off);
                q += __shfl_xor(q, off);
            }
            ls[reg] = s; lq[reg] = q;
        }
        if (r16 == 0) {
            #pragma unroll
            for (int reg = 0; reg < 4; ++reg) {
                int r = quad * 4 + reg;
                redS[w][r] = ls[reg];
                redQ[w][r] = lq[reg];
            }
        }
        __syncthreads();                    // B1
        #pragma unroll
        for (int reg = 0; reg < 4; ++reg) {
            int r = quad * 4 + reg;
            float s = redS[0][r] + redS[1][r] + redS[2][r] + redS[3][r];
            float q = redQ[0][r] + redQ[1][r] + redQ[2][r] + redQ[3][r];
            float mu = s * (1.f / 256.f);
            float var = q * (1.f / 256.f) - mu * mu;
            float rstd = rsqrtf(var + 1e-5f);
            #pragma unroll
            for (int nt = 0; nt < 4; ++nt) {
                int col = w * 64 + nt * 16 + r16;
                float val = (vv1[reg][nt] - mu) * rstd * g1[col] + b1[col];
                vv1[reg][nt] = val;
                x1s[r * 264 + col] = (__bf16)val;
            }
        }
    }
    __syncthreads();                        // B2 (x1s visible to all waves)

    // ---- stage B: h = relu(x1·W1^T + b1); wave w owns cols w*128..+127 --
    f32x4 hacc[8] = {};
    {
        const __bf16* wf = W1 + lane * 8;
        #pragma unroll
        for (int kc = 0; kc < 8; ++kc) {
            bf16x8 af = *(const bf16x8*)(&x1s[r16 * 264 + kc * 32 + quad * 8]);
            #pragma unroll
            for (int nt = 0; nt < 8; ++nt) {
                bf16x8 bfr = *(const bf16x8*)(wf + ((((w * 8 + nt) << 3) + kc) << 9));
                hacc[nt] = __builtin_amdgcn_mfma_f32_16x16x32_bf16(af, bfr, hacc[nt], 0, 0, 0);
            }
        }
    }
    #pragma unroll
    for (int nt = 0; nt < 8; ++nt) {
        int col = w * 128 + nt * 16 + r16;
        float bb = fb1[col];
        #pragma unroll
        for (int reg = 0; reg < 4; ++reg) {
            float v = fmaxf(hacc[nt][reg] + bb, 0.f);
            hs[(quad * 4 + reg) * 520 + col] = (__bf16)v;
        }
    }
    __syncthreads();                        // B3

    // ---- stage C: T = h·W2^T (K=512); wave w owns cols w*64..+63 --------
    f32x4 cacc[4] = {};
    {
        const __bf16* wf = W2 + lane * 8;
        #pragma unroll
        for (int kc = 0; kc < 16; ++kc) {
            bf16x8 af = *(const bf16x8*)(&hs[r16 * 520 + kc * 32 + quad * 8]);
            #pragma unroll
            for (int nt = 0; nt < 4; ++nt) {
                bf16x8 bfr = *(const bf16x8*)(wf + ((((w * 4 + nt) << 4) + kc) << 9));
                cacc[nt] = __builtin_amdgcn_mfma_f32_16x16x32_bf16(af, bfr, cacc[nt], 0, 0, 0);
            }
        }
    }

    // LN2 epilogue: residual x1 comes straight from vv1 registers.
    {
        float vvc[4][4];
        float ls[4], lq[4];
        #pragma unroll
        for (int reg = 0; reg < 4; ++reg) {
            float s = 0.f, q = 0.f;
            #pragma unroll
            for (int nt = 0; nt < 4; ++nt) {
                int col = w * 64 + nt * 16 + r16;
                float val = cacc[nt][reg] + fb2[col] + vv1[reg][nt];
                vvc[reg][nt] = val;
                s += val; q += val * val;
            }
            #pragma unroll
            for (int off = 1; off < 16; off <<= 1) {
                s += __shfl_xor(s, off);
                q += __shfl_xor(q, off);
            }
            ls[reg] = s; lq[reg] = q;
        }
        __syncthreads();   // B4: protect redS/redQ reuse
        if (r16 == 0) {
            #pragma unroll
            for (int reg = 0; reg < 4; ++reg) {
                int r = quad * 4 + reg;
                redS[w][r] = ls[reg];
                redQ[w][r] = lq[reg];
            }
        }
        __syncthreads();                    // B5
        #pragma unroll
        for (int reg = 0; reg < 4; ++reg) {
            int r = quad * 4 + reg;
            int m = m0 + r;
            float s = redS[0][r] + redS[1][r] + redS[2][r] + redS[3][r];
            float q = redQ[0][r] + redQ[1][r] + redQ[2][r] + redQ[3][r];
            float mu = s * (1.f / 256.f);
            float var = q * (1.f / 256.f) - mu * mu;
            float rstd = rsqrtf(var + 1e-5f);
            #pragma unroll
            for (int nt = 0; nt < 4; ++nt) {
                int col = w * 64 + nt * 16 + r16;
                float val = (vvc[reg][nt] - mu) * rstd * g2[col] + b2[col];
                if (wx32) xo[(size_t)m * 256 + col] = val;
                xo_bf[(size_t)m * 256 + col] = (__bf16)val;
            }
        }
    }
}

// ---------------------------------------------------------------------------
// MFMA flash attention v7 (proven, R7): QBLK=128, grid (4,128). Each wave
// owns TWO Q-tiles sharing ONE K-fragment prefetch set; whole-V^T staged
// once; ONE barrier per block.
// ---------------------------------------------------------------------------
#define VSL 520
#define PS 72

__global__ __launch_bounds__(256) void attn_mfma_kernel(
    const __bf16* __restrict__ qkv, __bf16* __restrict__ o)
{
    __shared__ __bf16 Vt[32 * VSL];        // 33.3 KB, V^T for all 512 keys
    __shared__ __bf16 Ps[4][2][16 * PS];   // 18.4 KB, per-wave per-qtile P

    int tid  = threadIdx.x;
    int w    = tid >> 6, lane = tid & 63;
    int quad = lane >> 4, r16 = lane & 15;
    int qt = blockIdx.x;            // 0..3
    int bh = blockIdx.y;            // 0..127
    int b = bh >> 3, h = bh & 7;
    int base = b * S_;
    int q0 = qt * 128;

    bf16x8 qa[2];
    #pragma unroll
    for (int u = 0; u < 2; ++u)
        qa[u] = *(const bf16x8*)(
            qkv + (size_t)(base + q0 + u * 64 + w * 16 + r16) * 768 + h * 32 + quad * 8);

    int kp  = tid & 31;
    int cch = (tid >> 5) & 3;
    int jh  = tid >> 7;
    const __bf16* vbase = qkv + (size_t)base * 768 + 512 + h * 32 + cch * 8;
    const __bf16* kbase = qkv + (size_t)base * 768 + 256 + h * 32 + quad * 8;

    // ---- stage entire V^T once ------------------------------------------
    #pragma unroll
    for (int kt2 = 0; kt2 < 8; kt2 += 2) {
        bf16x8 a0 = *(const bf16x8*)(vbase + (size_t)(kt2 * 64 + 2 * kp) * 768);
        bf16x8 a1 = *(const bf16x8*)(vbase + (size_t)(kt2 * 64 + 2 * kp + 1) * 768);
        bf16x8 b0 = *(const bf16x8*)(vbase + (size_t)((kt2 + 1) * 64 + 2 * kp) * 768);
        bf16x8 b1 = *(const bf16x8*)(vbase + (size_t)((kt2 + 1) * 64 + 2 * kp + 1) * 768);
        #pragma unroll
        for (int j = 0; j < 4; ++j) {
            int jj = jh * 4 + j;
            int d = cch * 8 + jj;
            union { __bf16 hh[2]; unsigned int u; } p0, p1;
            p0.hh[0] = a0[jj]; p0.hh[1] = a1[jj];
            p1.hh[0] = b0[jj]; p1.hh[1] = b1[jj];
            *(unsigned int*)(&Vt[d * VSL + kt2 * 64 + 2 * kp]) = p0.u;
            *(unsigned int*)(&Vt[d * VSL + (kt2 + 1) * 64 + 2 * kp]) = p1.u;
        }
    }

    // K prefetch for kt=0 (shared by both Q-tiles)
    bf16x8 kb[4], kbn[4];
    #pragma unroll
    for (int t = 0; t < 4; ++t)
        kbn[t] = *(const bf16x8*)(kbase + (size_t)(t * 16 + r16) * 768);

    f32x4 oacc[2][2] = {};
    float l_i[2][4] = {};

    __syncthreads();   // single barrier: Vt visible to all waves

    for (int kt = 0; kt < 8; ++kt) {
        #pragma unroll
        for (int t = 0; t < 4; ++t) kb[t] = kbn[t];
        if (kt < 7) {
            int off = (kt + 1) * 64;
            #pragma unroll
            for (int t = 0; t < 4; ++t)
                kbn[t] = *(const bf16x8*)(kbase + (size_t)(off + t * 16 + r16) * 768);
        }

        // QK^T: 8 independent MFMAs (2 Q-tiles x 4 key-subtiles), one kb set
        f32x4 s[2][4];
        #pragma unroll
        for (int u = 0; u < 2; ++u)
            #pragma unroll
            for (int t = 0; t < 4; ++t)
                s[u][t] = __builtin_amdgcn_mfma_f32_16x16x32_bf16(
                    qa[u], kb[t], (f32x4){0.f, 0.f, 0.f, 0.f}, 0, 0, 0);

        #pragma unroll
        for (int u = 0; u < 2; ++u) {
            #pragma unroll
            for (int r = 0; r < 4; ++r) {
                float p0 = __expf(s[u][0][r]), p1 = __expf(s[u][1][r]);
                float p2 = __expf(s[u][2][r]), p3 = __expf(s[u][3][r]);
                l_i[u][r] += (p0 + p1) + (p2 + p3);
                __bf16* pw = &Ps[w][u][(quad * 4 + r) * PS + r16];
                pw[0]  = (__bf16)p0;
                pw[16] = (__bf16)p1;
                pw[32] = (__bf16)p2;
                pw[48] = (__bf16)p3;
            }
        }

        // PV: 8 MFMAs (2 Q-tiles x 2 key-chunks x 2 d-halves), shared Vt
        #pragma unroll
        for (int u = 0; u < 2; ++u) {
            #pragma unroll
            for (int c = 0; c < 2; ++c) {
                bf16x8 pa  = *(const bf16x8*)(&Ps[w][u][r16 * PS + c * 32 + quad * 8]);
                bf16x8 vb0 = *(const bf16x8*)(&Vt[r16 * VSL + kt * 64 + c * 32 + quad * 8]);
                bf16x8 vb1 = *(const bf16x8*)(&Vt[(16 + r16) * VSL + kt * 64 + c * 32 + quad * 8]);
                oacc[u][0] = __builtin_amdgcn_mfma_f32_16x16x32_bf16(pa, vb0, oacc[u][0], 0, 0, 0);
                oacc[u][1] = __builtin_amdgcn_mfma_f32_16x16x32_bf16(pa, vb1, oacc[u][1], 0, 0, 0);
            }
        }
    }

    #pragma unroll
    for (int u = 0; u < 2; ++u) {
        #pragma unroll
        for (int r = 0; r < 4; ++r) {
            float ls = l_i[u][r];
            #pragma unroll
            for (int off = 1; off < 16; off <<= 1) ls += __shfl_xor(ls, off);
            float inv = 1.0f / ls;
            int q = base + q0 + u * 64 + w * 16 + quad * 4 + r;
            __bf16* op = o + (size_t)q * 256 + h * 32;
            op[r16]      = (__bf16)(oacc[u][0][r] * inv);
            op[16 + r16] = (__bf16)(oacc[u][1][r] * inv);
        }
    }
}

// ---------------------------------------------------------------------------
// MFMA edge predictions.
// ---------------------------------------------------------------------------
#define PP 264

__global__ __launch_bounds__(256) void pred_mfma(
    const __bf16* __restrict__ xbf, const int* __restrict__ ep,
    const int* __restrict__ en, const __bf16* __restrict__ Wp,
    const float* __restrict__ pe_b, const float* __restrict__ pt_b,
    float* __restrict__ out)
{
    __shared__ __bf16 P[4][16 * PP];   // 33 KB
    int tid = threadIdx.x;
    int w = tid >> 6, lane = tid & 63, quad = lane >> 4, r16 = lane & 15;
    int isPos = blockIdx.x < 512;
    int e0 = (blockIdx.x & 511) * 64 + w * 16;
    const int* epair = isPos ? ep : en;

    int half = lane >> 5;
    int col = (lane & 31) * 8;
    #pragma unroll
    for (int j = 0; j < 8; ++j) {
        int je = j * 2 + half;
        int e = e0 + je;
        int a = epair[2 * e], c = epair[2 * e + 1];
        bf16x8 av = *(const bf16x8*)(xbf + (size_t)a * 256 + col);
        bf16x8 cv = *(const bf16x8*)(xbf + (size_t)c * 256 + col);
        bf16x8 pv;
        #pragma unroll
        for (int t = 0; t < 8; ++t)
            pv[t] = (__bf16)((float)av[t] * (float)cv[t]);
        *(bf16x8*)(&P[w][je * PP + col]) = pv;
    }
    __syncthreads();

    f32x4 acc1 = {0.f, 0.f, 0.f, 0.f};
    f32x4 acc2 = {0.f, 0.f, 0.f, 0.f};
    #pragma unroll
    for (int k0 = 0; k0 < 256; k0 += 32) {
        bf16x8 af = *(const bf16x8*)(&P[w][r16 * PP + k0 + quad * 8]);
        bf16x8 b2 = *(const bf16x8*)(Wp + (size_t)(16 + r16) * 256 + k0 + quad * 8);
        acc2 = __builtin_amdgcn_mfma_f32_16x16x32_bf16(af, b2, acc2, 0, 0, 0);
        if (isPos) {
            bf16x8 b1 = *(const bf16x8*)(Wp + (size_t)r16 * 256 + k0 + quad * 8);
            acc1 = __builtin_amdgcn_mfma_f32_16x16x32_bf16(af, b1, acc1, 0, 0, 0);
        }
    }

    float* pred_pos = out;
    float* pred_neg = out + NE_;
    float* pred_type = out + 2 * NE_;
    float peb = pe_b[0];
    if (isPos) {
        float ptbv = pt_b[r16];
        #pragma unroll
        for (int reg = 0; reg < 4; ++reg) {
            int e = e0 + quad * 4 + reg;
            pred_type[(size_t)e * 16 + r16] = acc1[reg] + ptbv;
        }
        if (r16 == 0) {
            #pragma unroll
            for (int reg = 0; reg < 4; ++reg)
                pred_pos[e0 + quad * 4 + reg] = acc2[reg] + peb;
        }
    } else {
        if (r16 == 0) {
            #pragma unroll
            for (int reg = 0; reg < 4; ++reg)
                pred_neg[e0 + quad * 4 + reg] = acc2[reg] + peb;
        }
    }
}

// ---------------------------------------------------------------------------
extern "C" void kernel_launch(void* const* d_in, const int* in_sizes, int n_in,
                              void* d_out, int out_size, void* d_ws, size_t ws_size,
                              hipStream_t stream)
{
    const float* node_emb  = (const float*)d_in[0];
    const float* edge_emb  = (const float*)d_in[1];
    const int*   incidence = (const int*)d_in[2];
    const int*   edges_neg = (const int*)d_in[4];
    const int*   edges_pos = (const int*)d_in[5];
    const float* msg_w1    = (const float*)d_in[6];
    const float* msg_w2    = (const float*)d_in[7];
    const float* msg_b     = (const float*)d_in[8];
    const float* pos_table = (const float*)d_in[9];
    const float* in_proj_w = (const float*)d_in[10];
    const float* in_proj_b = (const float*)d_in[11];
    const float* out_w     = (const float*)d_in[12];
    const float* out_b     = (const float*)d_in[13];
    const float* ln1_g     = (const float*)d_in[14];
    const float* ln1_b     = (const float*)d_in[15];
    const float* ff_w1     = (const float*)d_in[16];
    const float* ff_b1     = (const float*)d_in[17];
    const float* ff_w2     = (const float*)d_in[18];
    const float* ff_b2     = (const float*)d_in[19];
    const float* ln2_g     = (const float*)d_in[20];
    const float* ln2_b     = (const float*)d_in[21];
    const float* pe_w      = (const float*)d_in[22];
    const float* pe_b      = (const float*)d_in[23];
    const float* pt_w      = (const float*)d_in[24];
    const float* pt_b      = (const float*)d_in[25];

    // workspace layout (~48.4 MB)
    float*  x       = (float*)d_ws;                       // N*D fp32 (8 MB)
    __bf16* x_bf    = (__bf16*)(x + (size_t)N_ * D_);     // N*D bf16 (4 MB)
    __bf16* ipw_bf  = x_bf + (size_t)N_ * D_;             // 4*768*256 (1.5 MB)
    __bf16* ow_bf   = ipw_bf + 786432;                    // 4*256*256 (0.5 MB)
    __bf16* fw1_bf  = ow_bf + 262144;                     // 4*512*256 (1 MB)
    __bf16* fw2_bf  = fw1_bf + 524288;                    // 4*256*512 (1 MB)
    __bf16* wcat_bf = fw2_bf + 524288;                    // 256*512  (0.25 MB)
    __bf16* wp_bf   = wcat_bf + 131072;                   // 32*256   (16 KB)
    float*  ipb_s   = (float*)(wp_bf + 8192);             // 4*768 fp32 (12 KB)
    float*  scratch = ipb_s + 3072;                       // 24 MB union:
    int*    cnt     = (int*)scratch;                      // 8192
    int*    row_ptr = cnt + 8192;                         // 8193
    int*    ofs     = row_ptr + 8200;                     // 8192
    int*    elist   = ofs + 8192;                         // 65536
    __bf16* qkv_bf = (__bf16*)scratch;                    // N*768 (12 MB)
    __bf16* o_bf   = qkv_bf + (size_t)N_ * 768;           // N*D   (4 MB)
    __bf16* G_bf   = (__bf16*)(scratch + 6291456);        // +24 MB: N*512 bf16 (8 MB)

    // 0. weight conversions (q pre-scaled, ow/fw1/fw2 fragment-swizzled)
    convert_all<<<2195, 256, 0, stream>>>(
        in_proj_w, ipw_bf, out_w, ow_bf, ff_w1, fw1_bf, ff_w2, fw2_bf,
        msg_w1, msg_w2, wcat_bf, pt_w, pe_w, wp_bf, in_proj_b, ipb_s, cnt);

    // 1. CSR build over destination nodes (incidence[0])
    hist_kernel<<<E_ / 256, 256, 0, stream>>>(incidence, cnt);
    scan_kernel<<<1, 256, 0, stream>>>(cnt, row_ptr, ofs);
    fill_kernel<<<E_ / 256, 256, 0, stream>>>(incidence, ofs, elist);

    // 2. gather-sum -> G_bf (atomics-free); agreg GEMM fused with
    //    x = node + pos + agreg (32-row tiles, 512 blocks)
    csr_gather<<<N_ / 4, 256, 0, stream>>>(
        node_emb, edge_emb, incidence, row_ptr, elist, G_bf);
    agreg_gemm<<<dim3(2, N_ / 32), 256, 0, stream>>>(
        G_bf, wcat_bf, row_ptr, msg_b, node_emb, pos_table, x, x_bf);

    // 3. transformer layers: QKV proj (staged) -> attention (QBLK=128) -> tail
    for (int li = 0; li < L_; ++li) {
        gemm_mfma<__bf16><<<dim3(768 / 128, N_ / 64), 256, 0, stream>>>(
            x_bf, ipw_bf + (size_t)li * 768 * 256, ipb_s + li * 768,
            qkv_bf, N_, 768, 256, 0);
        attn_mfma_kernel<<<dim3(S_ / 128, B_ * H_), 256, 0, stream>>>(qkv_bf, o_bf);
        tail_fused<<<N_ / 16, 256, 0, stream>>>(
            o_bf, ow_bf + (size_t)li * 65536, out_b + li * 256,
            x, ln1_g + li * 256, ln1_b + li * 256,
            fw1_bf + (size_t)li * 131072, ff_b1 + li * 512,
            fw2_bf + (size_t)li * 131072, ff_b2 + li * 256,
            ln2_g + li * 256, ln2_b + li * 256,
            x, x_bf, li == L_ - 1 ? 0 : 1);
    }

    // 4. MFMA edge predictions
    pred_mfma<<<1024, 256, 0, stream>>>(
        x_bf, edges_pos, edges_neg, wp_bf, pe_b, pt_b, (float*)d_out);
}

// Round 12
// 383.633 us; speedup vs baseline: 1.0559x; 1.0388x over previous
//
#include <hip/hip_runtime.h>
#include <hip/hip_bf16.h>

// Shapes (fixed by the reference)
#define B_  16
#define S_  512
#define D_  256
#define H_  8
#define L_  4
#define K_  16
#define N_  (B_ * S_)     // 8192
#define E_  65536
#define NE_ 32768
#define DFF_ 512
#define HD_ 32

typedef __attribute__((ext_vector_type(8))) __bf16 bf16x8;
typedef __attribute__((ext_vector_type(4))) __bf16 bf16x4;
typedef __attribute__((ext_vector_type(4))) float f32x4;

// async global->LDS, 16B per lane. LDS dest must be lane-contiguous (base+lane*16).
__device__ __forceinline__ void gl2lds16(const void* g, void* l) {
    __builtin_amdgcn_global_load_lds(
        (const __attribute__((address_space(1))) unsigned int*)g,
        (__attribute__((address_space(3))) unsigned int*)l, 16, 0, 0);
}

#define QSCALE 0.17677669529663688f   // 1/sqrt(32), folded into wq/bq

// ---------------------------------------------------------------------------
// Combined fp32 -> bf16 conversion for weights (1 launch) + cnt zeroing.
// ow/fw1/fw2 are stored MFMA-FRAGMENT-SWIZZLED: fragment (rg, kc) holds, at
// lane l, elements W[rg*16 + (l&15)][kc*32 + (l>>4)*8 .. +8], flat address
// layer_base + (rg*KC + kc)*512 + l*8. A wave's fragment load is then one
// contiguous 1 KB read (perfect coalescing, no LDS staging needed).
// in_proj stays LINEAR (the staged qkv GEMM wants gl2lds16-able rows).
// ---------------------------------------------------------------------------
__global__ __launch_bounds__(256) void convert_all(
    const float* __restrict__ ipw, __bf16* __restrict__ ipw_bf,
    const float* __restrict__ ow,  __bf16* __restrict__ ow_bf,
    const float* __restrict__ fw1, __bf16* __restrict__ fw1_bf,
    const float* __restrict__ fw2, __bf16* __restrict__ fw2_bf,
    const float* __restrict__ mw1, const float* __restrict__ mw2,
    __bf16* __restrict__ wcat_bf,
    const float* __restrict__ ptw, const float* __restrict__ pew,
    __bf16* __restrict__ wp_bf,
    const float* __restrict__ ipb, float* __restrict__ ipb_s,
    int* __restrict__ cnt)
{
    int blk = blockIdx.x;
    if (blk < 768) {
        // in_proj_w with q-row scaling (linear layout)
        size_t i = ((size_t)blk * 256 + threadIdx.x) * 4;
        int row = (int)((i >> 8) % 768);
        float sc = (row < 256) ? QSCALE : 1.0f;
        float4 v = *(const float4*)(ipw + i);
        bf16x4 o = {(__bf16)(v.x * sc), (__bf16)(v.y * sc),
                    (__bf16)(v.z * sc), (__bf16)(v.w * sc)};
        *(bf16x4*)(ipw_bf + i) = o;
    } else if (blk < 2048) {
        // ow / fw1 / fw2 -> fragment-swizzled bf16
        const float* src; __bf16* dst; int base;
        if      (blk < 1024)  { src = ow;   dst = ow_bf;   base = blk - 768; }
        else if (blk < 1536)  { src = fw1;  dst = fw1_bf;  base = blk - 1024; }
        else                  { src = fw2;  dst = fw2_bf;  base = blk - 1536; }
        size_t i = ((size_t)base * 256 + threadIdx.x) * 4;
        float4 v = *(const float4*)(src + i);
        int layer, row, col, kchunks; size_t lstride;
        if (blk < 1024) {            // ow: 4 x [256 x 256]
            layer = (int)(i >> 16); int idx = (int)(i & 65535);
            row = idx >> 8; col = idx & 255; kchunks = 8; lstride = 65536;
        } else if (blk < 1536) {     // fw1: 4 x [512 x 256]
            layer = (int)(i >> 17); int idx = (int)(i & 131071);
            row = idx >> 8; col = idx & 255; kchunks = 8; lstride = 131072;
        } else {                     // fw2: 4 x [256 x 512]
            layer = (int)(i >> 17); int idx = (int)(i & 131071);
            row = idx >> 9; col = idx & 511; kchunks = 16; lstride = 131072;
        }
        size_t dsti = (size_t)layer * lstride
                    + (size_t)((((row >> 4) * kchunks + (col >> 5)) << 9)
                               + ((col & 31) >> 3) * 128 + (row & 15) * 8 + (col & 7));
        bf16x4 o = {(__bf16)v.x, (__bf16)v.y, (__bf16)v.z, (__bf16)v.w};
        *(bf16x4*)(dst + dsti) = o;
    } else if (blk < 2176) {
        int isw2 = blk >= 2112;
        int base = blk - (isw2 ? 2112 : 2048);
        const float* src = isw2 ? mw2 : mw1;
        size_t i = ((size_t)base * 256 + threadIdx.x) * 4;   // elem in [256x256]
        int row = i >> 8, col = i & 255;
        float4 v = *(const float4*)(src + i);
        bf16x4 o = {(__bf16)v.x, (__bf16)v.y, (__bf16)v.z, (__bf16)v.w};
        *(bf16x4*)(wcat_bf + (size_t)row * 512 + (isw2 ? 256 : 0) + col) = o;
    } else if (blk < 2184) {
        int base = blk - 2176;
        size_t i = ((size_t)base * 256 + threadIdx.x) * 4;
        int row = i >> 8, col = i & 255;
        float4 v = make_float4(0.f, 0.f, 0.f, 0.f);
        if (row < 16)       v = *(const float4*)(ptw + row * 256 + col);
        else if (row == 16) v = *(const float4*)(pew + col);
        bf16x4 o = {(__bf16)v.x, (__bf16)v.y, (__bf16)v.z, (__bf16)v.w};
        *(bf16x4*)(wp_bf + i) = o;
    } else if (blk < 2187) {
        // scaled in_proj bias: 4*768 = 3072 floats, 3 blocks
        int base = blk - 2184;
        size_t i = ((size_t)base * 256 + threadIdx.x) * 4;
        if (i < 3072) {
            float sc = ((i % 768) < 256) ? QSCALE : 1.0f;
            float4 v = *(const float4*)(ipb + i);
            *(float4*)(ipb_s + i) = make_float4(v.x * sc, v.y * sc, v.z * sc, v.w * sc);
        }
    } else {
        int base = blk - 2187;
        int4* p = (int4*)(cnt + ((size_t)base * 256 + threadIdx.x) * 4);
        *p = make_int4(0, 0, 0, 0);
    }
}

// ---------------------------------------------------------------------------
// CSR build over destination nodes: histogram -> scan -> bucket fill.
// ---------------------------------------------------------------------------
__global__ __launch_bounds__(256) void hist_kernel(
    const int* __restrict__ inc, int* __restrict__ cnt)
{
    int e = blockIdx.x * 256 + threadIdx.x;
    atomicAdd(&cnt[inc[e]], 1);
}

__global__ __launch_bounds__(256) void scan_kernel(
    const int* __restrict__ cnt, int* __restrict__ row_ptr, int* __restrict__ ofs)
{
    __shared__ int part[256];
    int t = threadIdx.x;
    int base = t * 32, sum = 0;
    int local[32];
    #pragma unroll
    for (int j = 0; j < 32; ++j) { local[j] = cnt[base + j]; sum += local[j]; }
    part[t] = sum;
    __syncthreads();
    #pragma unroll
    for (int off = 1; off < 256; off <<= 1) {
        int other = (t >= off) ? part[t - off] : 0;
        __syncthreads();
        part[t] += other;
        __syncthreads();
    }
    int run = part[t] - sum;   // exclusive prefix
    for (int j = 0; j < 32; ++j) {
        row_ptr[base + j] = run;
        ofs[base + j] = run;
        run += local[j];
    }
    if (t == 255) row_ptr[8192] = run;
}

__global__ __launch_bounds__(256) void fill_kernel(
    const int* __restrict__ inc, int* __restrict__ ofs, int* __restrict__ elist)
{
    int e = blockIdx.x * 256 + threadIdx.x;
    int pos = atomicAdd(&ofs[inc[e]], 1);
    elist[pos] = e;
}

// ---------------------------------------------------------------------------
// CSR gather: G_bf[n][0:256] = sum node[inc1[e]], G_bf[n][256:512] = sum
// edge[e]. One wave per node, fp32 accumulate, 2-edge unroll for MLP.
// ---------------------------------------------------------------------------
__global__ __launch_bounds__(256) void csr_gather(
    const float* __restrict__ node, const float* __restrict__ edge,
    const int* __restrict__ inc, const int* __restrict__ row_ptr,
    const int* __restrict__ elist, __bf16* __restrict__ G)
{
    int n = blockIdx.x * 4 + (threadIdx.x >> 6);
    int lane = threadIdx.x & 63;
    int s = row_ptr[n], epos = row_ptr[n + 1];
    float4 an = {0.f, 0.f, 0.f, 0.f}, ae = {0.f, 0.f, 0.f, 0.f};
    int i = s;
    for (; i + 2 <= epos; i += 2) {
        int e0 = elist[i], e1 = elist[i + 1];
        int s0 = inc[E_ + e0], s1 = inc[E_ + e1];
        float4 nv0 = *(const float4*)(node + (size_t)s0 * 256 + lane * 4);
        float4 ev0 = *(const float4*)(edge + (size_t)e0 * 256 + lane * 4);
        float4 nv1 = *(const float4*)(node + (size_t)s1 * 256 + lane * 4);
        float4 ev1 = *(const float4*)(edge + (size_t)e1 * 256 + lane * 4);
        an.x += nv0.x + nv1.x; an.y += nv0.y + nv1.y;
        an.z += nv0.z + nv1.z; an.w += nv0.w + nv1.w;
        ae.x += ev0.x + ev1.x; ae.y += ev0.y + ev1.y;
        ae.z += ev0.z + ev1.z; ae.w += ev0.w + ev1.w;
    }
    if (i < epos) {
        int e0 = elist[i];
        int s0 = inc[E_ + e0];
        float4 nv0 = *(const float4*)(node + (size_t)s0 * 256 + lane * 4);
        float4 ev0 = *(const float4*)(edge + (size_t)e0 * 256 + lane * 4);
        an.x += nv0.x; an.y += nv0.y; an.z += nv0.z; an.w += nv0.w;
        ae.x += ev0.x; ae.y += ev0.y; ae.z += ev0.z; ae.w += ev0.w;
    }
    __bf16* g = G + (size_t)n * 512 + lane * 4;
    bf16x4 bn = {(__bf16)an.x, (__bf16)an.y, (__bf16)an.z, (__bf16)an.w};
    bf16x4 be = {(__bf16)ae.x, (__bf16)ae.y, (__bf16)ae.z, (__bf16)ae.w};
    *(bf16x4*)g = bn;
    *(bf16x4*)(g + 256) = be;
}

// ---------------------------------------------------------------------------
// bf16 MFMA GEMM: C[M,N] = A[M,K]·B[N,K]^T + bias (+relu), OutT epilogue cast.
// 64x128 tile, BK=64 via two stride-32 LDS regions per operand. (QKV proj)
// Proven structure: gl2lds16 staging + implicit multi-block overlap.
// ---------------------------------------------------------------------------
template <typename OutT>
__global__ __launch_bounds__(256) void gemm_mfma(
    const __bf16* __restrict__ A, const __bf16* __restrict__ Bw,
    const float* __restrict__ bias, OutT* __restrict__ C,
    int M, int N, int Kd, int relu)
{
    __shared__ __bf16 As0[64 * 32], As1[64 * 32];
    __shared__ __bf16 Bs0[128 * 32], Bs1[128 * 32];
    int tid = threadIdx.x;
    int m0 = blockIdx.y * 64, n0 = blockIdx.x * 128;
    int w = tid >> 6, lane = tid & 63, quad = lane >> 4, r16 = lane & 15;
    int wr = w >> 1, wc = w & 1;

    int lr = tid >> 2, lc = (tid & 3) * 8;
    const __bf16* ag  = A  + (size_t)(m0 + lr) * Kd + lc;
    const __bf16* bg0 = Bw + (size_t)(n0 + lr) * Kd + lc;
    const __bf16* bg1 = bg0 + (size_t)64 * Kd;

    f32x4 acc[2][4] = {};

    for (int k0 = 0; k0 < Kd; k0 += 64) {
        __syncthreads();
        gl2lds16(ag + k0,        As0 + tid * 8);
        gl2lds16(ag + k0 + 32,   As1 + tid * 8);
        gl2lds16(bg0 + k0,       Bs0 + tid * 8);
        gl2lds16(bg1 + k0,       Bs0 + 2048 + tid * 8);
        gl2lds16(bg0 + k0 + 32,  Bs1 + tid * 8);
        gl2lds16(bg1 + k0 + 32,  Bs1 + 2048 + tid * 8);
        __syncthreads();

        #pragma unroll
        for (int kh = 0; kh < 2; ++kh) {
            const __bf16* Asr = kh ? As1 : As0;
            const __bf16* Bsr = kh ? Bs1 : Bs0;
            bf16x8 af[2], bfr[4];
            #pragma unroll
            for (int mt = 0; mt < 2; ++mt)
                af[mt] = *(const bf16x8*)(Asr + (wr * 32 + mt * 16 + r16) * 32 + quad * 8);
            #pragma unroll
            for (int nt = 0; nt < 4; ++nt)
                bfr[nt] = *(const bf16x8*)(Bsr + (wc * 64 + nt * 16 + r16) * 32 + quad * 8);
            #pragma unroll
            for (int mt = 0; mt < 2; ++mt)
                #pragma unroll
                for (int nt = 0; nt < 4; ++nt)
                    acc[mt][nt] = __builtin_amdgcn_mfma_f32_16x16x32_bf16(
                        af[mt], bfr[nt], acc[mt][nt], 0, 0, 0);
        }
    }

    #pragma unroll
    for (int nt = 0; nt < 4; ++nt) {
        int n = n0 + wc * 64 + nt * 16 + r16;
        float bv = bias[n];
        #pragma unroll
        for (int mt = 0; mt < 2; ++mt) {
            #pragma unroll
            for (int reg = 0; reg < 4; ++reg) {
                int m = m0 + wr * 32 + mt * 16 + quad * 4 + reg;
                float v = acc[mt][nt][reg] + bv;
                if (relu) v = fmaxf(v, 0.f);
                C[(size_t)m * N + n] = (OutT)v;
            }
        }
    }
}

// ---------------------------------------------------------------------------
// agreg GEMM v2 (32-row tiles, grid (2,256) = 512 blocks for 2 blocks/CU):
// x[m,n] = G_bf[m,:]·wcat[n,:] + deg(m)*msg_b[n] + node[m,n] + pos[m%512,n]
// ---------------------------------------------------------------------------
__global__ __launch_bounds__(256) void agreg_gemm(
    const __bf16* __restrict__ G, const __bf16* __restrict__ Wc,
    const int* __restrict__ row_ptr, const float* __restrict__ mb,
    const float* __restrict__ node, const float* __restrict__ pos,
    float* __restrict__ xo, __bf16* __restrict__ xo_bf)
{
    __shared__ __bf16 As0[32 * 32], As1[32 * 32];      // 2 KB each
    __shared__ __bf16 Bs0[128 * 32], Bs1[128 * 32];    // 8 KB each
    int tid = threadIdx.x;
    int m0 = blockIdx.y * 32, n0 = blockIdx.x * 128;
    int w = tid >> 6, lane = tid & 63, quad = lane >> 4, r16 = lane & 15;
    int wr = w >> 1, wc = w & 1;

    int lr = tid >> 2, lc = (tid & 3) * 8;
    const __bf16* ag  = G  + (size_t)(m0 + (tid >> 2 & 31)) * 512 + lc;
    const __bf16* bg0 = Wc + (size_t)(n0 + lr) * 512 + lc;
    const __bf16* bg1 = bg0 + (size_t)64 * 512;

    f32x4 acc[4] = {};   // [nt], wave = 16 rows x 64 cols

    for (int k0 = 0; k0 < 512; k0 += 64) {
        __syncthreads();
        if (tid < 128) {
            gl2lds16(ag + k0,      As0 + tid * 8);
            gl2lds16(ag + k0 + 32, As1 + tid * 8);
        }
        gl2lds16(bg0 + k0,       Bs0 + tid * 8);
        gl2lds16(bg1 + k0,       Bs0 + 2048 + tid * 8);
        gl2lds16(bg0 + k0 + 32,  Bs1 + tid * 8);
        gl2lds16(bg1 + k0 + 32,  Bs1 + 2048 + tid * 8);
        __syncthreads();

        #pragma unroll
        for (int kh = 0; kh < 2; ++kh) {
            const __bf16* Asr = kh ? As1 : As0;
            const __bf16* Bsr = kh ? Bs1 : Bs0;
            bf16x8 af = *(const bf16x8*)(Asr + (wr * 16 + r16) * 32 + quad * 8);
            #pragma unroll
            for (int nt = 0; nt < 4; ++nt) {
                bf16x8 bfr = *(const bf16x8*)(Bsr + (wc * 64 + nt * 16 + r16) * 32 + quad * 8);
                acc[nt] = __builtin_amdgcn_mfma_f32_16x16x32_bf16(af, bfr, acc[nt], 0, 0, 0);
            }
        }
    }

    #pragma unroll
    for (int nt = 0; nt < 4; ++nt) {
        int n = n0 + wc * 64 + nt * 16 + r16;
        float mbv = mb[n];
        #pragma unroll
        for (int reg = 0; reg < 4; ++reg) {
            int m = m0 + wr * 16 + quad * 4 + reg;
            float deg = (float)(row_ptr[m + 1] - row_ptr[m]);
            float v = acc[nt][reg] + deg * mbv
                    + node[(size_t)m * 256 + n] + pos[(size_t)(m & 511) * 256 + n];
            xo[(size_t)m * 256 + n] = v;
            xo_bf[(size_t)m * 256 + n] = (__bf16)v;
        }
    }
}

// ---------------------------------------------------------------------------
// FUSED per-layer tail v4 (proven, R5): direct frag-swizzled weight loads,
// 6 barriers, LDS only for o-tile / x1 / h. Bit-identical to v1 chain.
// ---------------------------------------------------------------------------
__global__ __launch_bounds__(256) void tail_fused(
    const __bf16* __restrict__ A,      // o_bf [8192 x 256]
    const __bf16* __restrict__ Wo,     // frag-swizzled [256 x 256]
    const float* __restrict__ ob,      // out_b [256]
    const float* __restrict__ res,     // x fp32 [8192 x 256]
    const float* __restrict__ g1, const float* __restrict__ b1,
    const __bf16* __restrict__ W1,     // frag-swizzled [512 x 256]
    const float* __restrict__ fb1,     // [512]
    const __bf16* __restrict__ W2,     // frag-swizzled [256 x 512]
    const float* __restrict__ fb2,     // [256]
    const float* __restrict__ g2, const float* __restrict__ b2,
    float* __restrict__ xo, __bf16* __restrict__ xo_bf, int wx32)
{
    __shared__ __bf16 As[16 * 264];    // 8.25 KB o-tile
    __shared__ __bf16 x1s[16 * 264];   // 8.25 KB
    __shared__ __bf16 hs[16 * 520];    // 16.25 KB
    __shared__ float redS[4][16], redQ[4][16];

    int tid = threadIdx.x;
    int m0 = blockIdx.x * 16;
    int w = tid >> 6, lane = tid & 63, quad = lane >> 4, r16 = lane & 15;

    // ---- stage o tile into LDS (reg-staged, padded rows) ----------------
    #pragma unroll
    for (int rpt = 0; rpt < 2; ++rpt) {
        int c = tid + rpt * 256;            // 512 chunks of 16B
        int row = c >> 5, cc = c & 31;
        bf16x8 v = *(const bf16x8*)(A + (size_t)(m0 + row) * 256 + cc * 8);
        *(bf16x8*)(&As[row * 264 + cc * 8]) = v;
    }
    __syncthreads();                        // B0

    // ---- stage A: T = o·Wo^T (K=256); wave w owns cols w*64..+63 --------
    f32x4 acc[4] = {};
    {
        const __bf16* wf = Wo + lane * 8;
        #pragma unroll
        for (int kc = 0; kc < 8; ++kc) {
            bf16x8 af = *(const bf16x8*)(&As[r16 * 264 + kc * 32 + quad * 8]);
            #pragma unroll
            for (int nt = 0; nt < 4; ++nt) {
                bf16x8 bfr = *(const bf16x8*)(wf + ((((w * 4 + nt) << 3) + kc) << 9));
                acc[nt] = __builtin_amdgcn_mfma_f32_16x16x32_bf16(af, bfr, acc[nt], 0, 0, 0);
            }
        }
    }

    // LN1: vv1 holds fp32 x1 (residual for LN2); bf16 copy goes to x1s.
    float vv1[4][4];
    {
        float ls[4], lq[4];
        #pragma unroll
        for (int reg = 0; reg < 4; ++reg) {
            int m = m0 + quad * 4 + reg;
            float s = 0.f, q = 0.f;
            #pragma unroll
            for (int nt = 0; nt < 4; ++nt) {
                int col = w * 64 + nt * 16 + r16;
                float val = acc[nt][reg] + ob[col] + res[(size_t)m * 256 + col];
                vv1[reg][nt] = val;
                s += val; q += val * val;
            }
            #pragma unroll
            for (int off = 1; off < 16; off <<= 1) {
                s += __shfl_xor(s, off);
                q += __shfl_xor(q, off);
            }
            ls[reg] = s; lq[reg] = q;
        }
        if (r16 == 0) {
            #pragma unroll
            for (int reg = 0; reg < 4; ++reg) {
                int r = quad * 4 + reg;
                redS[w][r] = ls[reg];
                redQ[w][r] = lq[reg];
            }
        }
        __syncthreads();                    // B1
        #pragma unroll
        for (int reg = 0; reg < 4; ++reg) {
            int r = quad * 4 + reg;
            float s = redS[0][r] + redS[1][r] + redS[2][r] + redS[3][r];
            float q = redQ[0][r] + redQ[1][r] + redQ[2][r] + redQ[3][r];
            float mu = s * (1.f / 256.f);
            float var = q * (1.f / 256.f) - mu * mu;
            float rstd = rsqrtf(var + 1e-5f);
            #pragma unroll
            for (int nt = 0; nt < 4; ++nt) {
                int col = w * 64 + nt * 16 + r16;
                float val = (vv1[reg][nt] - mu) * rstd * g1[col] + b1[col];
                vv1[reg][nt] = val;
                x1s[r * 264 + col] = (__bf16)val;
            }
        }
    }
    __syncthreads();                        // B2 (x1s visible to all waves)

    // ---- stage B: h = relu(x1·W1^T + b1); wave w owns cols w*128..+127 --
    f32x4 hacc[8] = {};
    {
        const __bf16* wf = W1 + lane * 8;
        #pragma unroll
        for (int kc = 0; kc < 8; ++kc) {
            bf16x8 af = *(const bf16x8*)(&x1s[r16 * 264 + kc * 32 + quad * 8]);
            #pragma unroll
            for (int nt = 0; nt < 8; ++nt) {
                bf16x8 bfr = *(const bf16x8*)(wf + ((((w * 8 + nt) << 3) + kc) << 9));
                hacc[nt] = __builtin_amdgcn_mfma_f32_16x16x32_bf16(af, bfr, hacc[nt], 0, 0, 0);
            }
        }
    }
    #pragma unroll
    for (int nt = 0; nt < 8; ++nt) {
        int col = w * 128 + nt * 16 + r16;
        float bb = fb1[col];
        #pragma unroll
        for (int reg = 0; reg < 4; ++reg) {
            float v = fmaxf(hacc[nt][reg] + bb, 0.f);
            hs[(quad * 4 + reg) * 520 + col] = (__bf16)v;
        }
    }
    __syncthreads();                        // B3

    // ---- stage C: T = h·W2^T (K=512); wave w owns cols w*64..+63 --------
    f32x4 cacc[4] = {};
    {
        const __bf16* wf = W2 + lane * 8;
        #pragma unroll
        for (int kc = 0; kc < 16; ++kc) {
            bf16x8 af = *(const bf16x8*)(&hs[r16 * 520 + kc * 32 + quad * 8]);
            #pragma unroll
            for (int nt = 0; nt < 4; ++nt) {
                bf16x8 bfr = *(const bf16x8*)(wf + ((((w * 4 + nt) << 4) + kc) << 9));
                cacc[nt] = __builtin_amdgcn_mfma_f32_16x16x32_bf16(af, bfr, cacc[nt], 0, 0, 0);
            }
        }
    }

    // LN2 epilogue: residual x1 comes straight from vv1 registers.
    {
        float vvc[4][4];
        float ls[4], lq[4];
        #pragma unroll
        for (int reg = 0; reg < 4; ++reg) {
            float s = 0.f, q = 0.f;
            #pragma unroll
            for (int nt = 0; nt < 4; ++nt) {
                int col = w * 64 + nt * 16 + r16;
                float val = cacc[nt][reg] + fb2[col] + vv1[reg][nt];
                vvc[reg][nt] = val;
                s += val; q += val * val;
            }
            #pragma unroll
            for (int off = 1; off < 16; off <<= 1) {
                s += __shfl_xor(s, off);
                q += __shfl_xor(q, off);
            }
            ls[reg] = s; lq[reg] = q;
        }
        __syncthreads();   // B4: protect redS/redQ reuse
        if (r16 == 0) {
            #pragma unroll
            for (int reg = 0; reg < 4; ++reg) {
                int r = quad * 4 + reg;
                redS[w][r] = ls[reg];
                redQ[w][r] = lq[reg];
            }
        }
        __syncthreads();                    // B5
        #pragma unroll
        for (int reg = 0; reg < 4; ++reg) {
            int r = quad * 4 + reg;
            int m = m0 + r;
            float s = redS[0][r] + redS[1][r] + redS[2][r] + redS[3][r];
            float q = redQ[0][r] + redQ[1][r] + redQ[2][r] + redQ[3][r];
            float mu = s * (1.f / 256.f);
            float var = q * (1.f / 256.f) - mu * mu;
            float rstd = rsqrtf(var + 1e-5f);
            #pragma unroll
            for (int nt = 0; nt < 4; ++nt) {
                int col = w * 64 + nt * 16 + r16;
                float val = (vvc[reg][nt] - mu) * rstd * g2[col] + b2[col];
                if (wx32) xo[(size_t)m * 256 + col] = val;
                xo_bf[(size_t)m * 256 + col] = (__bf16)val;
            }
        }
    }
}

// ---------------------------------------------------------------------------
// MFMA flash attention v8: QBLK=256, 512 threads (8 waves), grid (2,128) =
// 256 blocks. Per-wave work identical to v7 (2 Q-tiles, shared K-prefetch),
// but V^T-staging redundancy halves again (2 blocks per (b,h) vs 4) and
// occupancy rises to 16 waves/CU (2 blocks x 8 waves, LDS 70.1 KB).
// Staging: two 256-thread halves each stage 4 kt-tiles with the exact v7
// packing -> identical LDS contents; per-row accumulation order unchanged
// -> bit-identical results.
// ---------------------------------------------------------------------------
#define VSL 520
#define PS 72

__global__ __launch_bounds__(512) void attn_mfma_kernel(
    const __bf16* __restrict__ qkv, __bf16* __restrict__ o)
{
    __shared__ __bf16 Vt[32 * VSL];        // 33.3 KB, V^T for all 512 keys
    __shared__ __bf16 Ps[8][2][16 * PS];   // 36.9 KB, per-wave per-qtile P

    int tid  = threadIdx.x;
    int w    = tid >> 6, lane = tid & 63;
    int quad = lane >> 4, r16 = lane & 15;
    int qt = blockIdx.x;            // 0..1
    int bh = blockIdx.y;            // 0..127
    int b = bh >> 3, h = bh & 7;
    int base = b * S_;
    int q0 = qt * 256;

    bf16x8 qa[2];
    #pragma unroll
    for (int u = 0; u < 2; ++u)
        qa[u] = *(const bf16x8*)(
            qkv + (size_t)(base + q0 + u * 128 + w * 16 + r16) * 768 + h * 32 + quad * 8);

    // staging ids: two 256-thread halves, each stages 4 kt tiles (v7 packing)
    int t2   = tid & 255;
    int half = tid >> 8;            // 0 -> kts 0..3, 1 -> kts 4..7
    int kp  = t2 & 31;
    int cch = (t2 >> 5) & 3;
    int jh  = t2 >> 7;
    const __bf16* vbase = qkv + (size_t)base * 768 + 512 + h * 32 + cch * 8;
    const __bf16* kbase = qkv + (size_t)base * 768 + 256 + h * 32 + quad * 8;

    // ---- stage entire V^T once ------------------------------------------
    #pragma unroll
    for (int i2 = 0; i2 < 2; ++i2) {
        int kt2 = half * 4 + i2 * 2;
        bf16x8 a0 = *(const bf16x8*)(vbase + (size_t)(kt2 * 64 + 2 * kp) * 768);
        bf16x8 a1 = *(const bf16x8*)(vbase + (size_t)(kt2 * 64 + 2 * kp + 1) * 768);
        bf16x8 b0 = *(const bf16x8*)(vbase + (size_t)((kt2 + 1) * 64 + 2 * kp) * 768);
        bf16x8 b1 = *(const bf16x8*)(vbase + (size_t)((kt2 + 1) * 64 + 2 * kp + 1) * 768);
        #pragma unroll
        for (int j = 0; j < 4; ++j) {
            int jj = jh * 4 + j;
            int d = cch * 8 + jj;
            union { __bf16 hh[2]; unsigned int u; } p0, p1;
            p0.hh[0] = a0[jj]; p0.hh[1] = a1[jj];
            p1.hh[0] = b0[jj]; p1.hh[1] = b1[jj];
            *(unsigned int*)(&Vt[d * VSL + kt2 * 64 + 2 * kp]) = p0.u;
            *(unsigned int*)(&Vt[d * VSL + (kt2 + 1) * 64 + 2 * kp]) = p1.u;
        }
    }

    // K prefetch for kt=0 (shared by both Q-tiles of this wave)
    bf16x8 kb[4], kbn[4];
    #pragma unroll
    for (int t = 0; t < 4; ++t)
        kbn[t] = *(const bf16x8*)(kbase + (size_t)(t * 16 + r16) * 768);

    f32x4 oacc[2][2] = {};
    float l_i[2][4] = {};

    __syncthreads();   // single barrier: Vt visible to all waves

    for (int kt = 0; kt < 8; ++kt) {
        #pragma unroll
        for (int t = 0; t < 4; ++t) kb[t] = kbn[t];
        if (kt < 7) {
            int off = (kt + 1) * 64;
            #pragma unroll
            for (int t = 0; t < 4; ++t)
                kbn[t] = *(const bf16x8*)(kbase + (size_t)(off + t * 16 + r16) * 768);
        }

        // QK^T: 8 independent MFMAs (2 Q-tiles x 4 key-subtiles), one kb set
        f32x4 s[2][4];
        #pragma unroll
        for (int u = 0; u < 2; ++u)
            #pragma unroll
            for (int t = 0; t < 4; ++t)
                s[u][t] = __builtin_amdgcn_mfma_f32_16x16x32_bf16(
                    qa[u], kb[t], (f32x4){0.f, 0.f, 0.f, 0.f}, 0, 0, 0);

        #pragma unroll
        for (int u = 0; u < 2; ++u) {
            #pragma unroll
            for (int r = 0; r < 4; ++r) {
                float p0 = __expf(s[u][0][r]), p1 = __expf(s[u][1][r]);
                float p2 = __expf(s[u][2][r]), p3 = __expf(s[u][3][r]);
                l_i[u][r] += (p0 + p1) + (p2 + p3);
                __bf16* pw = &Ps[w][u][(quad * 4 + r) * PS + r16];
                pw[0]  = (__bf16)p0;
                pw[16] = (__bf16)p1;
                pw[32] = (__bf16)p2;
                pw[48] = (__bf16)p3;
            }
        }

        // PV: 8 MFMAs (2 Q-tiles x 2 key-chunks x 2 d-halves), shared Vt
        #pragma unroll
        for (int u = 0; u < 2; ++u) {
            #pragma unroll
            for (int c = 0; c < 2; ++c) {
                bf16x8 pa  = *(const bf16x8*)(&Ps[w][u][r16 * PS + c * 32 + quad * 8]);
                bf16x8 vb0 = *(const bf16x8*)(&Vt[r16 * VSL + kt * 64 + c * 32 + quad * 8]);
                bf16x8 vb1 = *(const bf16x8*)(&Vt[(16 + r16) * VSL + kt * 64 + c * 32 + quad * 8]);
                oacc[u][0] = __builtin_amdgcn_mfma_f32_16x16x32_bf16(pa, vb0, oacc[u][0], 0, 0, 0);
                oacc[u][1] = __builtin_amdgcn_mfma_f32_16x16x32_bf16(pa, vb1, oacc[u][1], 0, 0, 0);
            }
        }
    }

    #pragma unroll
    for (int u = 0; u < 2; ++u) {
        #pragma unroll
        for (int r = 0; r < 4; ++r) {
            float ls = l_i[u][r];
            #pragma unroll
            for (int off = 1; off < 16; off <<= 1) ls += __shfl_xor(ls, off);
            float inv = 1.0f / ls;
            int q = base + q0 + u * 128 + w * 16 + quad * 4 + r;
            __bf16* op = o + (size_t)q * 256 + h * 32;
            op[r16]      = (__bf16)(oacc[u][0][r] * inv);
            op[16 + r16] = (__bf16)(oacc[u][1][r] * inv);
        }
    }
}

// ---------------------------------------------------------------------------
// MFMA edge predictions.
// ---------------------------------------------------------------------------
#define PP 264

__global__ __launch_bounds__(256) void pred_mfma(
    const __bf16* __restrict__ xbf, const int* __restrict__ ep,
    const int* __restrict__ en, const __bf16* __restrict__ Wp,
    const float* __restrict__ pe_b, const float* __restrict__ pt_b,
    float* __restrict__ out)
{
    __shared__ __bf16 P[4][16 * PP];   // 33 KB
    int tid = threadIdx.x;
    int w = tid >> 6, lane = tid & 63, quad = lane >> 4, r16 = lane & 15;
    int isPos = blockIdx.x < 512;
    int e0 = (blockIdx.x & 511) * 64 + w * 16;
    const int* epair = isPos ? ep : en;

    int half = lane >> 5;
    int col = (lane & 31) * 8;
    #pragma unroll
    for (int j = 0; j < 8; ++j) {
        int je = j * 2 + half;
        int e = e0 + je;
        int a = epair[2 * e], c = epair[2 * e + 1];
        bf16x8 av = *(const bf16x8*)(xbf + (size_t)a * 256 + col);
        bf16x8 cv = *(const bf16x8*)(xbf + (size_t)c * 256 + col);
        bf16x8 pv;
        #pragma unroll
        for (int t = 0; t < 8; ++t)
            pv[t] = (__bf16)((float)av[t] * (float)cv[t]);
        *(bf16x8*)(&P[w][je * PP + col]) = pv;
    }
    __syncthreads();

    f32x4 acc1 = {0.f, 0.f, 0.f, 0.f};
    f32x4 acc2 = {0.f, 0.f, 0.f, 0.f};
    #pragma unroll
    for (int k0 = 0; k0 < 256; k0 += 32) {
        bf16x8 af = *(const bf16x8*)(&P[w][r16 * PP + k0 + quad * 8]);
        bf16x8 b2 = *(const bf16x8*)(Wp + (size_t)(16 + r16) * 256 + k0 + quad * 8);
        acc2 = __builtin_amdgcn_mfma_f32_16x16x32_bf16(af, b2, acc2, 0, 0, 0);
        if (isPos) {
            bf16x8 b1 = *(const bf16x8*)(Wp + (size_t)r16 * 256 + k0 + quad * 8);
            acc1 = __builtin_amdgcn_mfma_f32_16x16x32_bf16(af, b1, acc1, 0, 0, 0);
        }
    }

    float* pred_pos = out;
    float* pred_neg = out + NE_;
    float* pred_type = out + 2 * NE_;
    float peb = pe_b[0];
    if (isPos) {
        float ptbv = pt_b[r16];
        #pragma unroll
        for (int reg = 0; reg < 4; ++reg) {
            int e = e0 + quad * 4 + reg;
            pred_type[(size_t)e * 16 + r16] = acc1[reg] + ptbv;
        }
        if (r16 == 0) {
            #pragma unroll
            for (int reg = 0; reg < 4; ++reg)
                pred_pos[e0 + quad * 4 + reg] = acc2[reg] + peb;
        }
    } else {
        if (r16 == 0) {
            #pragma unroll
            for (int reg = 0; reg < 4; ++reg)
                pred_neg[e0 + quad * 4 + reg] = acc2[reg] + peb;
        }
    }
}

// ---------------------------------------------------------------------------
extern "C" void kernel_launch(void* const* d_in, const int* in_sizes, int n_in,
                              void* d_out, int out_size, void* d_ws, size_t ws_size,
                              hipStream_t stream)
{
    const float* node_emb  = (const float*)d_in[0];
    const float* edge_emb  = (const float*)d_in[1];
    const int*   incidence = (const int*)d_in[2];
    const int*   edges_neg = (const int*)d_in[4];
    const int*   edges_pos = (const int*)d_in[5];
    const float* msg_w1    = (const float*)d_in[6];
    const float* msg_w2    = (const float*)d_in[7];
    const float* msg_b     = (const float*)d_in[8];
    const float* pos_table = (const float*)d_in[9];
    const float* in_proj_w = (const float*)d_in[10];
    const float* in_proj_b = (const float*)d_in[11];
    const float* out_w     = (const float*)d_in[12];
    const float* out_b     = (const float*)d_in[13];
    const float* ln1_g     = (const float*)d_in[14];
    const float* ln1_b     = (const float*)d_in[15];
    const float* ff_w1     = (const float*)d_in[16];
    const float* ff_b1     = (const float*)d_in[17];
    const float* ff_w2     = (const float*)d_in[18];
    const float* ff_b2     = (const float*)d_in[19];
    const float* ln2_g     = (const float*)d_in[20];
    const float* ln2_b     = (const float*)d_in[21];
    const float* pe_w      = (const float*)d_in[22];
    const float* pe_b      = (const float*)d_in[23];
    const float* pt_w      = (const float*)d_in[24];
    const float* pt_b      = (const float*)d_in[25];

    // workspace layout (~48.4 MB)
    float*  x       = (float*)d_ws;                       // N*D fp32 (8 MB)
    __bf16* x_bf    = (__bf16*)(x + (size_t)N_ * D_);     // N*D bf16 (4 MB)
    __bf16* ipw_bf  = x_bf + (size_t)N_ * D_;             // 4*768*256 (1.5 MB)
    __bf16* ow_bf   = ipw_bf + 786432;                    // 4*256*256 (0.5 MB)
    __bf16* fw1_bf  = ow_bf + 262144;                     // 4*512*256 (1 MB)
    __bf16* fw2_bf  = fw1_bf + 524288;                    // 4*256*512 (1 MB)
    __bf16* wcat_bf = fw2_bf + 524288;                    // 256*512  (0.25 MB)
    __bf16* wp_bf   = wcat_bf + 131072;                   // 32*256   (16 KB)
    float*  ipb_s   = (float*)(wp_bf + 8192);             // 4*768 fp32 (12 KB)
    float*  scratch = ipb_s + 3072;                       // 24 MB union:
    int*    cnt     = (int*)scratch;                      // 8192
    int*    row_ptr = cnt + 8192;                         // 8193
    int*    ofs     = row_ptr + 8200;                     // 8192
    int*    elist   = ofs + 8192;                         // 65536
    __bf16* qkv_bf = (__bf16*)scratch;                    // N*768 (12 MB)
    __bf16* o_bf   = qkv_bf + (size_t)N_ * 768;           // N*D   (4 MB)
    __bf16* G_bf   = (__bf16*)(scratch + 6291456);        // +24 MB: N*512 bf16 (8 MB)

    // 0. weight conversions (q pre-scaled, ow/fw1/fw2 fragment-swizzled)
    convert_all<<<2195, 256, 0, stream>>>(
        in_proj_w, ipw_bf, out_w, ow_bf, ff_w1, fw1_bf, ff_w2, fw2_bf,
        msg_w1, msg_w2, wcat_bf, pt_w, pe_w, wp_bf, in_proj_b, ipb_s, cnt);

    // 1. CSR build over destination nodes (incidence[0])
    hist_kernel<<<E_ / 256, 256, 0, stream>>>(incidence, cnt);
    scan_kernel<<<1, 256, 0, stream>>>(cnt, row_ptr, ofs);
    fill_kernel<<<E_ / 256, 256, 0, stream>>>(incidence, ofs, elist);

    // 2. gather-sum -> G_bf (atomics-free); agreg GEMM fused with
    //    x = node + pos + agreg (32-row tiles, 512 blocks)
    csr_gather<<<N_ / 4, 256, 0, stream>>>(
        node_emb, edge_emb, incidence, row_ptr, elist, G_bf);
    agreg_gemm<<<dim3(2, N_ / 32), 256, 0, stream>>>(
        G_bf, wcat_bf, row_ptr, msg_b, node_emb, pos_table, x, x_bf);

    // 3. transformer layers: QKV proj (staged) -> attention (QBLK=256) -> tail
    for (int li = 0; li < L_; ++li) {
        gemm_mfma<__bf16><<<dim3(768 / 128, N_ / 64), 256, 0, stream>>>(
            x_bf, ipw_bf + (size_t)li * 768 * 256, ipb_s + li * 768,
            qkv_bf, N_, 768, 256, 0);
        attn_mfma_kernel<<<dim3(S_ / 256, B_ * H_), 512, 0, stream>>>(qkv_bf, o_bf);
        tail_fused<<<N_ / 16, 256, 0, stream>>>(
            o_bf, ow_bf + (size_t)li * 65536, out_b + li * 256,
            x, ln1_g + li * 256, ln1_b + li * 256,
            fw1_bf + (size_t)li * 131072, ff_b1 + li * 512,
            fw2_bf + (size_t)li * 131072, ff_b2 + li * 256,
            ln2_g + li * 256, ln2_b + li * 256,
            x, x_bf, li == L_ - 1 ? 0 : 1);
    }

    // 4. MFMA edge predictions
    pred_mfma<<<1024, 256, 0, stream>>>(
        x_bf, edges_pos, edges_neg, wp_bf, pe_b, pt_b, (float*)d_out);
}